// Round 5
// baseline (5905.261 us; speedup 1.0000x reference)
//
#include <hip/hip_runtime.h>
#include <math.h>

#define NEGV -1e9f
#define SK_TAU 0.05f

typedef __attribute__((ext_vector_type(4))) float f32x4;
typedef __attribute__((ext_vector_type(8))) short short8;

// ---------------- bf16 split helpers ----------------
__device__ inline unsigned bf16rtn(float x) {
    unsigned u = __float_as_uint(x);
    return (u + 0x7FFFu + ((u >> 16) & 1u)) >> 16;
}
__device__ inline float bf2f(short h) {
    return __uint_as_float(((unsigned)(unsigned short)h) << 16);
}
__device__ inline void split1(float x, short& h, short& l) {
    unsigned hu = bf16rtn(x);
    h = (short)hu;
    float r = x - __uint_as_float(hu << 16);
    l = (short)(__float_as_uint(r) >> 16);
}
__device__ inline void cvt4(const float4 v, short4& h, short4& l) {
    unsigned h0 = bf16rtn(v.x), h1 = bf16rtn(v.y), h2 = bf16rtn(v.z), h3 = bf16rtn(v.w);
    h.x = (short)h0; h.y = (short)h1; h.z = (short)h2; h.w = (short)h3;
    float l0 = v.x - __uint_as_float(h0 << 16);
    float l1 = v.y - __uint_as_float(h1 << 16);
    float l2 = v.z - __uint_as_float(h2 << 16);
    float l3 = v.w - __uint_as_float(h3 << 16);
    l.x = (short)(__float_as_uint(l0) >> 16);
    l.y = (short)(__float_as_uint(l1) >> 16);
    l.z = (short)(__float_as_uint(l2) >> 16);
    l.w = (short)(__float_as_uint(l3) >> 16);
}

// ---------------- inv column L1 norm ----------------
__global__ __launch_bounds__(256) void colnorm_k(const float* __restrict__ A,
                                                 float* __restrict__ inv)
{
    int idx = blockIdx.x * 256 + threadIdx.x;
    int b = idx >> 8, m = idx & 255;
    const float* p = A + (long long)b * 65536 + m;
    float s = 0.f;
    #pragma unroll 8
    for (int n = 0; n < 256; ++n) s += fabsf(p[n * 256]);
    inv[idx] = 1.f / fmaxf(s, 1e-12f);
}

// ---------------- fp32 -> split planes (row-major copy) ----------------
__global__ __launch_bounds__(256) void split_mat(const float* __restrict__ X,
                                                 short* __restrict__ H,
                                                 short* __restrict__ L, long long n4)
{
    long long i = (long long)blockIdx.x * 256 + threadIdx.x;
    long long stride = (long long)gridDim.x * 256;
    for (; i < n4; i += stride) {
        float4 v = ((const float4*)X)[i];
        short4 h, l;
        cvt4(v, h, l);
        ((short4*)H)[i] = h;
        ((short4*)L)[i] = l;
    }
}

// ---------------- weight slice -> transposed split planes ----------------
// W fp32 [Krows][2048] (row stride ldw=2048), cols [c0, c0+ncols) ->
// H/L planes [ncols][Krows].
__global__ __launch_bounds__(256) void wsplit_t(const float* __restrict__ W, int ldw, int c0,
                                                short* __restrict__ H, short* __restrict__ L,
                                                int K)
{
    __shared__ float tile[32][33];
    int kt = blockIdx.x * 32, ct = blockIdx.y * 32;
    int tx = threadIdx.x & 31, ty = threadIdx.x >> 5;   // ty 0..7
    #pragma unroll
    for (int i = 0; i < 4; ++i)
        tile[ty + 8 * i][tx] = W[(long long)(kt + ty + 8 * i) * ldw + c0 + ct + tx];
    __syncthreads();
    #pragma unroll
    for (int i = 0; i < 4; ++i) {
        int nn = ty + 8 * i, kk = tx;
        float v = tile[kk][nn];
        short h, l;
        split1(v, h, l);
        long long o = (long long)(ct + nn) * K + kt + kk;
        H[o] = h; L[o] = l;
    }
}

// ---------------- split-bf16 MFMA GEMM ----------------
// C = epi( A[M,K] @ B[K,N] ), 3 products (AhBh + AhBl + AlBh).
// A: split planes [M][K].  B: BS ? transposed split planes [N][K]
//                              : fp32 [K][NB] converted in-kernel.
// OM: 0 = fp32 store, 1 = split store, 2 = split accumulate.
// Block 128x128x32, 4 waves (2x2 of 64x64), LDS rows RS=36 shorts (proven 0-conflict).
#define RS 36

template <int OM, bool BS>
__global__ __launch_bounds__(256, 2) void gemm_mfma(
    const short* __restrict__ Ah_, const short* __restrict__ Al_,
    const short* __restrict__ Bh_, const short* __restrict__ Bl_,
    const float* __restrict__ Bf_, int K, int NB,
    float* __restrict__ Cf, short* __restrict__ Ch, short* __restrict__ Cl, int ldC,
    const float* __restrict__ bias, int relu)
{
    __shared__ short AhS[128 * RS];
    __shared__ short AlS[128 * RS];
    __shared__ short BhS[128 * RS];
    __shared__ short BlS[128 * RS];

    const int tid = threadIdx.x;
    const int wave = tid >> 6, L = tid & 63;
    const int m0 = blockIdx.y * 128, n0 = blockIdx.x * 128;
    const int wm = (wave & 1) * 64, wn = (wave >> 1) * 64;

    const int row = tid & 127;
    const int h16 = (tid >> 7) * 16;

    const short* ap_h = Ah_ + (long long)(m0 + row) * K + h16;
    const short* ap_l = Al_ + (long long)(m0 + row) * K + h16;
    const short* bp_h = BS ? Bh_ + (long long)(n0 + row) * K + h16 : nullptr;
    const short* bp_l = BS ? Bl_ + (long long)(n0 + row) * K + h16 : nullptr;

    // !BS staging map (round-4 proven)
    const int bn  = tid & 127;
    const int bkb = (tid >> 7) * 4;
    const float* bf0 = BS ? nullptr : Bf_ + (long long)bkb * NB + n0 + bn;

    f32x4 acc[4][4];
    #pragma unroll
    for (int i = 0; i < 4; ++i)
        #pragma unroll
        for (int j = 0; j < 4; ++j)
            acc[i][j] = (f32x4){0.f, 0.f, 0.f, 0.f};

    short8 pah[2], pal[2], pbh[2], pbl[2];
    float braw[16];
    short4 bh4[4], bl4[4];

    // ---- prologue ----
    #pragma unroll
    for (int j = 0; j < 2; ++j) {
        pah[j] = *(const short8*)(ap_h + j * 8);
        pal[j] = *(const short8*)(ap_l + j * 8);
    }
    if (BS) {
        #pragma unroll
        for (int j = 0; j < 2; ++j) {
            pbh[j] = *(const short8*)(bp_h + j * 8);
            pbl[j] = *(const short8*)(bp_l + j * 8);
        }
    } else {
        #pragma unroll
        for (int g = 0; g < 4; ++g)
            #pragma unroll
            for (int i = 0; i < 4; ++i)
                braw[g * 4 + i] = bf0[(long long)(g * 8 + i) * NB];
        #pragma unroll
        for (int g = 0; g < 4; ++g) {
            float4 v = {braw[g * 4 + 0], braw[g * 4 + 1], braw[g * 4 + 2], braw[g * 4 + 3]};
            cvt4(v, bh4[g], bl4[g]);
        }
    }

    for (int k0 = 0; k0 < K; k0 += 32) {
        __syncthreads();
        // ---- store staged panel to LDS ----
        #pragma unroll
        for (int j = 0; j < 2; ++j) {
            *(short4*)&AhS[row * RS + h16 + j * 8 + 0] = *(((const short4*)&pah[j]) + 0);
            *(short4*)&AhS[row * RS + h16 + j * 8 + 4] = *(((const short4*)&pah[j]) + 1);
            *(short4*)&AlS[row * RS + h16 + j * 8 + 0] = *(((const short4*)&pal[j]) + 0);
            *(short4*)&AlS[row * RS + h16 + j * 8 + 4] = *(((const short4*)&pal[j]) + 1);
        }
        if (BS) {
            #pragma unroll
            for (int j = 0; j < 2; ++j) {
                *(short4*)&BhS[row * RS + h16 + j * 8 + 0] = *(((const short4*)&pbh[j]) + 0);
                *(short4*)&BhS[row * RS + h16 + j * 8 + 4] = *(((const short4*)&pbh[j]) + 1);
                *(short4*)&BlS[row * RS + h16 + j * 8 + 0] = *(((const short4*)&pbl[j]) + 0);
                *(short4*)&BlS[row * RS + h16 + j * 8 + 4] = *(((const short4*)&pbl[j]) + 1);
            }
        } else {
            #pragma unroll
            for (int g = 0; g < 4; ++g) {
                *(short4*)&BhS[bn * RS + bkb + g * 8] = bh4[g];
                *(short4*)&BlS[bn * RS + bkb + g * 8] = bl4[g];
            }
        }
        __syncthreads();

        const bool more = (k0 + 32) < K;
        if (more) {
            #pragma unroll
            for (int j = 0; j < 2; ++j) {
                pah[j] = *(const short8*)(ap_h + k0 + 32 + j * 8);
                pal[j] = *(const short8*)(ap_l + k0 + 32 + j * 8);
            }
            if (BS) {
                #pragma unroll
                for (int j = 0; j < 2; ++j) {
                    pbh[j] = *(const short8*)(bp_h + k0 + 32 + j * 8);
                    pbl[j] = *(const short8*)(bp_l + k0 + 32 + j * 8);
                }
            } else {
                const float* bp = bf0 + (long long)(k0 + 32) * NB;
                #pragma unroll
                for (int g = 0; g < 4; ++g)
                    #pragma unroll
                    for (int i = 0; i < 4; ++i)
                        braw[g * 4 + i] = bp[(long long)(g * 8 + i) * NB];
            }
        }

        // ---- fragments + 48 MFMA ----
        short8 AF[4], ALF[4], BF[4], BLF[4];
        {
            int mb = (wm + (L & 15)) * RS + (L >> 4) * 8;
            int nb = (wn + (L & 15)) * RS + (L >> 4) * 8;
            #pragma unroll
            for (int t = 0; t < 4; ++t) {
                int ao = mb + t * 16 * RS;
                *(short4*)&AF[t]        = *(short4*)&AhS[ao];
                *((short4*)&AF[t] + 1)  = *(short4*)&AhS[ao + 4];
                *(short4*)&ALF[t]       = *(short4*)&AlS[ao];
                *((short4*)&ALF[t] + 1) = *(short4*)&AlS[ao + 4];
                int bo = nb + t * 16 * RS;
                *(short4*)&BF[t]        = *(short4*)&BhS[bo];
                *((short4*)&BF[t] + 1)  = *(short4*)&BhS[bo + 4];
                *(short4*)&BLF[t]       = *(short4*)&BlS[bo];
                *((short4*)&BLF[t] + 1) = *(short4*)&BlS[bo + 4];
            }
        }
        #pragma unroll
        for (int ti = 0; ti < 4; ++ti)
            #pragma unroll
            for (int tj = 0; tj < 4; ++tj) {
                acc[ti][tj] = __builtin_amdgcn_mfma_f32_16x16x32_bf16(AF[ti],  BF[tj],  acc[ti][tj], 0, 0, 0);
                acc[ti][tj] = __builtin_amdgcn_mfma_f32_16x16x32_bf16(AF[ti],  BLF[tj], acc[ti][tj], 0, 0, 0);
                acc[ti][tj] = __builtin_amdgcn_mfma_f32_16x16x32_bf16(ALF[ti], BF[tj],  acc[ti][tj], 0, 0, 0);
            }

        if (!BS && more) {
            #pragma unroll
            for (int g = 0; g < 4; ++g) {
                float4 v = {braw[g * 4 + 0], braw[g * 4 + 1], braw[g * 4 + 2], braw[g * 4 + 3]};
                cvt4(v, bh4[g], bl4[g]);
            }
        }
    }

    // ---- epilogue: C/D layout col = lane&15, row = (lane>>4)*4 + reg ----
    const int lcol = L & 15, lrow = (L >> 4) * 4;
    float bv[4];
    #pragma unroll
    for (int tj = 0; tj < 4; ++tj)
        bv[tj] = bias ? bias[n0 + wn + tj * 16 + lcol] : 0.f;

    #pragma unroll
    for (int ti = 0; ti < 4; ++ti) {
        #pragma unroll
        for (int r = 0; r < 4; ++r) {
            int grow = m0 + wm + ti * 16 + lrow + r;
            #pragma unroll
            for (int tj = 0; tj < 4; ++tj) {
                int gcol = n0 + wn + tj * 16 + lcol;
                float v = acc[ti][tj][r] + bv[tj];
                if (relu) v = fmaxf(v, 0.f);
                long long idx = (long long)grow * ldC + gcol;
                if (OM == 0) {
                    Cf[idx] = v;
                } else {
                    if (OM == 2) v += bf2f(Ch[idx]) + bf2f(Cl[idx]);
                    short hh, ll;
                    split1(v, hh, ll);
                    Ch[idx] = hh;
                    Cl[idx] = ll;
                }
            }
        }
    }
}

// ---------------- batched fp32 VALU GEMM (256x2048x256 per batch) ----------------
// C[z] = (TA ? A[z]^T : A[z] * colscale_k) @ B[z]  (+ C if ACC), split output.
// A fp32 (ld 256); B = split planes [8192][2048] (batch rows z*256..); C same layout.
template <bool TA, bool ACC>
__global__ __launch_bounds__(256, 2) void bgemm(
    const float* __restrict__ A,
    const short* __restrict__ Bh_, const short* __restrict__ Bl_,
    short* __restrict__ Ch, short* __restrict__ Cl,
    const float* __restrict__ colscale)
{
    __shared__ float As[16][132];
    __shared__ float Bs[16][132];

    const int N = 2048;
    const long long sB = 524288;
    int z = blockIdx.z;
    const float* Az = A + (long long)z * 65536;
    const float* cs = colscale ? colscale + z * 256 : nullptr;

    int n0 = blockIdx.x * 128, m0 = blockIdx.y * 128;
    int tid = threadIdx.x;
    int tx = tid & 15, ty = tid >> 4;

    float accv[8][8];
    #pragma unroll
    for (int i = 0; i < 8; ++i)
        #pragma unroll
        for (int j = 0; j < 8; ++j) accv[i][j] = 0.f;

    for (int k0 = 0; k0 < 256; k0 += 16) {
        if (!TA) {
            #pragma unroll
            for (int i = 0; i < 2; ++i) {
                int lin = tid + i * 256;
                int r  = lin >> 2;
                int c4 = (lin & 3) * 4;
                float4 v = *(const float4*)(Az + (long long)(m0 + r) * 256 + k0 + c4);
                if (cs) {
                    v.x *= cs[k0 + c4 + 0]; v.y *= cs[k0 + c4 + 1];
                    v.z *= cs[k0 + c4 + 2]; v.w *= cs[k0 + c4 + 3];
                }
                As[c4 + 0][r] = v.x; As[c4 + 1][r] = v.y;
                As[c4 + 2][r] = v.z; As[c4 + 3][r] = v.w;
            }
        } else {
            #pragma unroll
            for (int i = 0; i < 2; ++i) {
                int lin = tid + i * 256;
                int kk = lin >> 5;
                int m4 = (lin & 31) * 4;
                *(float4*)&As[kk][m4] =
                    *(const float4*)(Az + (long long)(k0 + kk) * 256 + m0 + m4);
            }
        }
        #pragma unroll
        for (int i = 0; i < 2; ++i) {
            int lin = tid + i * 256;
            int kk = lin >> 5;
            int n4 = (lin & 31) * 4;
            long long off = (long long)z * sB + (long long)(k0 + kk) * N + n0 + n4;
            short4 h = *(const short4*)(Bh_ + off);
            short4 l = *(const short4*)(Bl_ + off);
            Bs[kk][n4 + 0] = bf2f(h.x) + bf2f(l.x);
            Bs[kk][n4 + 1] = bf2f(h.y) + bf2f(l.y);
            Bs[kk][n4 + 2] = bf2f(h.z) + bf2f(l.z);
            Bs[kk][n4 + 3] = bf2f(h.w) + bf2f(l.w);
        }
        __syncthreads();

        #pragma unroll
        for (int kk = 0; kk < 16; ++kk) {
            float a[8], b[8];
            *(float4*)&a[0] = *(const float4*)&As[kk][ty * 8];
            *(float4*)&a[4] = *(const float4*)&As[kk][ty * 8 + 4];
            *(float4*)&b[0] = *(const float4*)&Bs[kk][tx * 8];
            *(float4*)&b[4] = *(const float4*)&Bs[kk][tx * 8 + 4];
            #pragma unroll
            for (int i = 0; i < 8; ++i)
                #pragma unroll
                for (int j = 0; j < 8; ++j)
                    accv[i][j] = fmaf(a[i], b[j], accv[i][j]);
        }
        __syncthreads();
    }

    #pragma unroll
    for (int i = 0; i < 8; ++i) {
        int rowl = m0 + ty * 8 + i;
        long long base = (long long)z * sB + (long long)rowl * N;
        #pragma unroll
        for (int j = 0; j < 8; ++j) {
            int col = n0 + tx * 8 + j;
            long long idx = base + col;
            float v = accv[i][j];
            if (ACC) v += bf2f(Ch[idx]) + bf2f(Cl[idx]);
            short hh, ll;
            split1(v, hh, ll);
            Ch[idx] = hh;
            Cl[idx] = ll;
        }
    }
}

// ---------------- fp64-accumulate affinity GEMM: S = A @ emb^T ----------------
// A fp32 [8192][2048]; B = emb split planes; C = S [32][256][256].
__global__ __launch_bounds__(256) void gemm_bt_f64(
    const float* __restrict__ A,
    const short* __restrict__ Bh_, const short* __restrict__ Bl_,
    float* __restrict__ C)
{
    __shared__ float As[16][65];
    __shared__ float Bs[16][65];

    const int K = 2048;
    int z = blockIdx.z;
    const float* Az = A + (long long)z * 524288;
    C += (long long)z * 65536;

    int n0 = blockIdx.x * 64;
    int m0 = blockIdx.y * 64;
    int tid = threadIdx.x;
    int tx = tid & 15;
    int ty = tid >> 4;

    double acc[4][4];
    #pragma unroll
    for (int i = 0; i < 4; ++i)
        #pragma unroll
        for (int j = 0; j < 4; ++j) acc[i][j] = 0.0;

    int r  = tid >> 2;
    int c4 = (tid & 3) * 4;

    for (int k0 = 0; k0 < K; k0 += 16) {
        {
            const float4 v = *(const float4*)(Az + (long long)(m0 + r) * K + k0 + c4);
            As[c4 + 0][r] = v.x; As[c4 + 1][r] = v.y;
            As[c4 + 2][r] = v.z; As[c4 + 3][r] = v.w;
        }
        {
            long long off = (long long)z * 524288 + (long long)(n0 + r) * K + k0 + c4;
            short4 h = *(const short4*)(Bh_ + off);
            short4 l = *(const short4*)(Bl_ + off);
            Bs[c4 + 0][r] = bf2f(h.x) + bf2f(l.x);
            Bs[c4 + 1][r] = bf2f(h.y) + bf2f(l.y);
            Bs[c4 + 2][r] = bf2f(h.z) + bf2f(l.z);
            Bs[c4 + 3][r] = bf2f(h.w) + bf2f(l.w);
        }
        __syncthreads();

        #pragma unroll
        for (int kk = 0; kk < 16; ++kk) {
            double a[4], b[4];
            #pragma unroll
            for (int i = 0; i < 4; ++i) a[i] = (double)As[kk][ty + 16 * i];
            #pragma unroll
            for (int j = 0; j < 4; ++j) b[j] = (double)Bs[kk][tx + 16 * j];
            #pragma unroll
            for (int i = 0; i < 4; ++i)
                #pragma unroll
                for (int j = 0; j < 4; ++j)
                    acc[i][j] = fma(a[i], b[j], acc[i][j]);
        }
        __syncthreads();
    }

    #pragma unroll
    for (int i = 0; i < 4; ++i) {
        int rowl = m0 + ty + 16 * i;
        #pragma unroll
        for (int j = 0; j < 4; ++j)
            C[(long long)rowl * 256 + n0 + tx + 16 * j] = (float)acc[i][j];
    }
}

// ---------------- Sinkhorn ----------------
__global__ __launch_bounds__(256) void sk_row(float* __restrict__ S,
                                              const int* __restrict__ n1, int init)
{
    int r = blockIdx.x * 4 + (threadIdx.x >> 6);
    int lane = threadIdx.x & 63;
    int b = r >> 8, n = r & 255;
    float* p = S + (long long)r * 256;
    int lim = n1[b];
    if (n >= lim) {
        float4 neg = {NEGV, NEGV, NEGV, NEGV};
        *(float4*)(p + lane * 4) = neg;
        return;
    }
    float4 v = *(const float4*)(p + lane * 4);
    if (init) {
        v.x /= SK_TAU; v.y /= SK_TAU; v.z /= SK_TAU; v.w /= SK_TAU;
    }
    float m = fmaxf(fmaxf(v.x, v.y), fmaxf(v.z, v.w));
    #pragma unroll
    for (int off = 1; off < 64; off <<= 1) m = fmaxf(m, __shfl_xor(m, off));
    float s = expf(v.x - m) + expf(v.y - m) + expf(v.z - m) + expf(v.w - m);
    #pragma unroll
    for (int off = 1; off < 64; off <<= 1) s += __shfl_xor(s, off);
    float lse = m + logf(s);
    v.x -= lse; v.y -= lse; v.z -= lse; v.w -= lse;
    *(float4*)(p + lane * 4) = v;
}

__global__ __launch_bounds__(64) void sk_col(float* __restrict__ S,
                                             const int* __restrict__ n1, int final_)
{
    int b = blockIdx.y;
    int m = blockIdx.x * 64 + threadIdx.x;
    float* base = S + (long long)b * 65536;
    int lim = n1[b];
    float mx = -3.4e38f, sum = 0.f;
    for (int n = 0; n < 256; ++n) {
        float x = base[n * 256 + m];
        float nm = fmaxf(mx, x);
        sum = sum * expf(mx - nm) + expf(x - nm);
        mx = nm;
    }
    float lse = mx + logf(sum);
    if (final_) {
        for (int n = 0; n < 256; ++n) {
            float x = base[n * 256 + m];
            base[n * 256 + m] = (n < lim) ? expf(x - lse) : 0.f;
        }
    } else {
        for (int n = 0; n < 256; ++n) {
            float x = base[n * 256 + m];
            base[n * 256 + m] = (n < lim) ? (x - lse) : NEGV;
        }
    }
}

static void sinkhorn(hipStream_t st, float* S, const int* n1)
{
    sk_row<<<2048, 256, 0, st>>>(S, n1, 1);
    for (int it = 1; it < 10; ++it) {
        if (it & 1)
            sk_col<<<dim3(4, 32), 64, 0, st>>>(S, n1, it == 9);
        else
            sk_row<<<2048, 256, 0, st>>>(S, n1, 0);
    }
}

// ---------------- launch wrappers ----------------
static void gsp(hipStream_t st, int om, const short* Ah, const short* Al,
                const short* Bh, const short* Bl, int Ns, int K,
                float* Cf, short* Ch, short* Cl, const float* bias, int relu)
{
    dim3 grid(Ns / 128, 64), block(256);
    if (om == 0)
        gemm_mfma<0, true><<<grid, block, 0, st>>>(Ah, Al, Bh, Bl, nullptr, K, 0, Cf, nullptr, nullptr, 2048, bias, relu);
    else if (om == 1)
        gemm_mfma<1, true><<<grid, block, 0, st>>>(Ah, Al, Bh, Bl, nullptr, K, 0, nullptr, Ch, Cl, 2048, bias, relu);
    else
        gemm_mfma<2, true><<<grid, block, 0, st>>>(Ah, Al, Bh, Bl, nullptr, K, 0, nullptr, Ch, Cl, 2048, bias, relu);
}

static void gsc(hipStream_t st, int om, const short* Ah, const short* Al,
                const float* Bf, short* Ch, short* Cl, const float* bias)
{
    dim3 grid(16, 64), block(256);
    if (om == 1)
        gemm_mfma<1, false><<<grid, block, 0, st>>>(Ah, Al, nullptr, nullptr, Bf, 2048, 2048, nullptr, Ch, Cl, 2048, bias, 0);
    else
        gemm_mfma<2, false><<<grid, block, 0, st>>>(Ah, Al, nullptr, nullptr, Bf, 2048, 2048, nullptr, Ch, Cl, 2048, bias, 0);
}

static void wsp(hipStream_t st, const float* W, int Krows, int c0, int ncols,
                short* H, short* L)
{
    dim3 grid(Krows / 32, ncols / 32);
    wsplit_t<<<grid, 256, 0, st>>>(W, 2048, c0, H, L, Krows);
}

// ---------------- driver ----------------
// d_ws: exactly 4 x 64 MiB (T1..T4). d_out (8 MiB): weight-split scratch /
// inv vectors / sinkhorn S, time-multiplexed (liveness audited per phase).
extern "C" void kernel_launch(void* const* d_in, const int* in_sizes, int n_in,
                              void* d_out, int out_size, void* d_ws, size_t ws_size,
                              hipStream_t stream)
{
    const float* feat1 = (const float*)d_in[0];
    const float* feat2 = (const float*)d_in[1];
    const float* A1    = (const float*)d_in[2];
    const float* A2    = (const float*)d_in[3];
    const int*   n1    = (const int*)d_in[4];
    const float* W0a = (const float*)d_in[8];  const float* b0a = (const float*)d_in[9];
    const float* W0u = (const float*)d_in[10]; const float* b0u = (const float*)d_in[11];
    const float* W1a = (const float*)d_in[12]; const float* b1a = (const float*)d_in[13];
    const float* W1u = (const float*)d_in[14]; const float* b1u = (const float*)d_in[15];
    const float* Wc  = (const float*)d_in[16]; const float* bc  = (const float*)d_in[17];
    const float* Aaff0 = (const float*)d_in[18];
    const float* Aaff1 = (const float*)d_in[19];

    const long long TSZ = 16777216LL;   // floats per big buffer
    const long long PL  = 16777216LL;   // shorts per [8192][2048] plane
    const long long PF  = 8388608LL;    // shorts per [8192][1024] plane

    float* T1f = (float*)d_ws;
    float* T2f = T1f + TSZ;
    float* T3f = T2f + TSZ;
    float* T4f = T3f + TSZ;
    short *T1h = (short*)T1f, *T1l = T1h + PL;
    short *T2h = (short*)T2f, *T2l = T2h + PL;
    short *T3h = (short*)T3f, *T3l = T3h + PL;
    short *T4h = (short*)T4f, *T4l = T4h + PL;

    // feat splits live in T4 during layer 0
    short* f1h = (short*)T4f;      short* f1l = f1h + PF;
    short* f2h = f1h + 2 * PF;     short* f2l = f1h + 3 * PF;
    // layer-0 inv vectors overlay dead feat1 region (head of T4)
    float* invA = (float*)T4f;
    float* invB = invA + 8192;

    float* S   = (float*)d_out;
    short* swh = (short*)d_out;          // weight-split scratch planes
    short* swl = swh + 2097152;
    float* inv1 = S;                     // layer-1 inv vectors (d_out head)
    float* inv2 = S + 8192;

    dim3 bgrid(16, 2, 32), bblk(256);

    // ===== Phase 0: split feats =====
    split_mat<<<2048, 256, 0, stream>>>(feat1, f1h, f1l, 8192LL * 1024 / 4);
    split_mat<<<2048, 256, 0, stream>>>(feat2, f2h, f2l, 8192LL * 1024 / 4);

    // ===== Phase 1: gconv layer 0 =====
    wsp(stream, W0u, 1024, 0, 2048, swh, swl);
    gsp(stream, 1, f1h, f1l, swh, swl, 2048, 1024, nullptr, T1h, T1l, b0u, 1);   // ux1
    gsp(stream, 1, f2h, f2l, swh, swl, 2048, 1024, nullptr, T2h, T2l, b0u, 1);   // ux2
    wsp(stream, W0a, 1024, 0, 2048, swh, swl);
    gsp(stream, 1, f1h, f1l, swh, swl, 2048, 1024, nullptr, T3h, T3l, b0a, 1);   // ax1 (feat1 dead)
    colnorm_k<<<32, 256, 0, stream>>>(A1, invA);
    colnorm_k<<<32, 256, 0, stream>>>(A2, invB);
    bgemm<false, true><<<bgrid, bblk, 0, stream>>>(A1, T3h, T3l, T1h, T1l, invA); // emb1
    gsp(stream, 1, f2h, f2l, swh, swl, 2048, 1024, nullptr, T3h, T3l, b0a, 1);   // ax2 (feat2 dead)
    bgemm<false, true><<<bgrid, bblk, 0, stream>>>(A2, T3h, T3l, T2h, T2l, invB); // emb2

    // ===== Phase 2: affinity 0  (d_out scratch free) =====
    wsp(stream, Aaff0, 2048, 0, 1024, swh, swl);
    gsp(stream, 0, T1h, T1l, swh, swl, 1024, 2048, T3f + 0, nullptr, nullptr, nullptr, 0);
    wsp(stream, Aaff0, 2048, 1024, 1024, swh, swl);
    gsp(stream, 0, T1h, T1l, swh, swl, 1024, 2048, T3f + 1024, nullptr, nullptr, nullptr, 0);
    gemm_bt_f64<<<dim3(4, 4, 32), 256, 0, stream>>>(T3f, T2h, T2l, S);

    sinkhorn(stream, S, n1);   // p in d_out

    // ===== Phase 4: cross-graph update =====
    bgemm<false, false><<<bgrid, bblk, 0, stream>>>(S, T2h, T2l, T3h, T3l, nullptr);   // c1 = p@emb2
    gsc(stream, 1, T1h, T1l, Wc,           T4h, T4l, bc);        // new1 = emb1@Wc_top + bc   (p alive: slow B)
    gsc(stream, 2, T3h, T3l, Wc + 4194304, T4h, T4l, nullptr);   // new1 += c1@Wc_bot
    bgemm<true, false><<<bgrid, bblk, 0, stream>>>(S, T1h, T1l, T3h, T3l, nullptr);    // c2 = p^T@emb1; p dead
    wsp(stream, Wc, 2048, 0, 1024, swh, swl);
    gsp(stream, 1, T2h, T2l, swh, swl, 1024, 2048, nullptr, T1h + 0,    T1l + 0,    bc, 0);
    wsp(stream, Wc, 2048, 1024, 1024, swh, swl);
    gsp(stream, 1, T2h, T2l, swh, swl, 1024, 2048, nullptr, T1h + 1024, T1l + 1024, bc + 1024, 0);
    wsp(stream, Wc + 4194304, 2048, 0, 1024, swh, swl);
    gsp(stream, 2, T3h, T3l, swh, swl, 1024, 2048, nullptr, T1h + 0,    T1l + 0,    nullptr, 0);
    wsp(stream, Wc + 4194304, 2048, 1024, 1024, swh, swl);
    gsp(stream, 2, T3h, T3l, swh, swl, 1024, 2048, nullptr, T1h + 1024, T1l + 1024, nullptr, 0);
    // new1 = T4, new2 = T1

    // ===== Phase 5: gconv layer 1 =====
    wsp(stream, W1a, 2048, 0, 1024, swh, swl);
    gsp(stream, 1, T4h, T4l, swh, swl, 1024, 2048, nullptr, T2h + 0,    T2l + 0,    b1a, 1);
    wsp(stream, W1a, 2048, 1024, 1024, swh, swl);
    gsp(stream, 1, T4h, T4l, swh, swl, 1024, 2048, nullptr, T2h + 1024, T2l + 1024, b1a + 1024, 1);  // ax1
    wsp(stream, W1u, 2048, 0, 1024, swh, swl);
    gsp(stream, 1, T4h, T4l, swh, swl, 1024, 2048, nullptr, T3h + 0,    T3l + 0,    b1u, 1);
    wsp(stream, W1u, 2048, 1024, 1024, swh, swl);
    gsp(stream, 1, T4h, T4l, swh, swl, 1024, 2048, nullptr, T3h + 1024, T3l + 1024, b1u + 1024, 1);  // ux1
    colnorm_k<<<32, 256, 0, stream>>>(A1, inv1);
    bgemm<false, true><<<bgrid, bblk, 0, stream>>>(A1, T2h, T2l, T3h, T3l, inv1);   // emb1f = T3 (new1 dead)
    wsp(stream, W1a, 2048, 0, 1024, swh, swl);
    gsp(stream, 1, T1h, T1l, swh, swl, 1024, 2048, nullptr, T2h + 0,    T2l + 0,    b1a, 1);
    wsp(stream, W1a, 2048, 1024, 1024, swh, swl);
    gsp(stream, 1, T1h, T1l, swh, swl, 1024, 2048, nullptr, T2h + 1024, T2l + 1024, b1a + 1024, 1);  // ax2
    wsp(stream, W1u, 2048, 0, 1024, swh, swl);
    gsp(stream, 1, T1h, T1l, swh, swl, 1024, 2048, nullptr, T4h + 0,    T4l + 0,    b1u, 1);
    wsp(stream, W1u, 2048, 1024, 1024, swh, swl);
    gsp(stream, 1, T1h, T1l, swh, swl, 1024, 2048, nullptr, T4h + 1024, T4l + 1024, b1u + 1024, 1);  // ux2
    colnorm_k<<<32, 256, 0, stream>>>(A2, inv2);
    bgemm<false, true><<<bgrid, bblk, 0, stream>>>(A2, T2h, T2l, T4h, T4l, inv2);   // emb2f = T4 (new2 dead)

    // ===== Phase 6: affinity 1 =====
    wsp(stream, Aaff1, 2048, 0, 1024, swh, swl);
    gsp(stream, 0, T3h, T3l, swh, swl, 1024, 2048, T1f + 0, nullptr, nullptr, nullptr, 0);
    wsp(stream, Aaff1, 2048, 1024, 1024, swh, swl);
    gsp(stream, 0, T3h, T3l, swh, swl, 1024, 2048, T1f + 1024, nullptr, nullptr, nullptr, 0);
    gemm_bt_f64<<<dim3(4, 4, 32), 256, 0, stream>>>(T1f, T4h, T4l, S);

    sinkhorn(stream, S, n1);   // final output in d_out
}

// Round 6
// 5509.465 us; speedup vs baseline: 1.0718x; 1.0718x over previous
//
#include <hip/hip_runtime.h>
#include <math.h>

#define NEGV -1e9f
#define SK_TAU 0.05f

typedef __attribute__((ext_vector_type(4))) float f32x4;
typedef __attribute__((ext_vector_type(8))) short short8;

#define GLDS(g, l) __builtin_amdgcn_global_load_lds( \
    (const __attribute__((address_space(1))) void*)(g), \
    (__attribute__((address_space(3))) void*)(l), 16, 0, 0)

// ---------------- bf16 split helpers ----------------
__device__ inline unsigned bf16rtn(float x) {
    unsigned u = __float_as_uint(x);
    return (u + 0x7FFFu + ((u >> 16) & 1u)) >> 16;
}
__device__ inline float bf2f(short h) {
    return __uint_as_float(((unsigned)(unsigned short)h) << 16);
}
__device__ inline void split1(float x, short& h, short& l) {
    unsigned hu = bf16rtn(x);
    h = (short)hu;
    float r = x - __uint_as_float(hu << 16);
    l = (short)(__float_as_uint(r) >> 16);
}
__device__ inline void cvt4(const float4 v, short4& h, short4& l) {
    unsigned h0 = bf16rtn(v.x), h1 = bf16rtn(v.y), h2 = bf16rtn(v.z), h3 = bf16rtn(v.w);
    h.x = (short)h0; h.y = (short)h1; h.z = (short)h2; h.w = (short)h3;
    float l0 = v.x - __uint_as_float(h0 << 16);
    float l1 = v.y - __uint_as_float(h1 << 16);
    float l2 = v.z - __uint_as_float(h2 << 16);
    float l3 = v.w - __uint_as_float(h3 << 16);
    l.x = (short)(__float_as_uint(l0) >> 16);
    l.y = (short)(__float_as_uint(l1) >> 16);
    l.z = (short)(__float_as_uint(l2) >> 16);
    l.w = (short)(__float_as_uint(l3) >> 16);
}

// ---------------- inv column L1 norm ----------------
__global__ __launch_bounds__(256) void colnorm_k(const float* __restrict__ A,
                                                 float* __restrict__ inv)
{
    int idx = blockIdx.x * 256 + threadIdx.x;
    int b = idx >> 8, m = idx & 255;
    const float* p = A + (long long)b * 65536 + m;
    float s = 0.f;
    #pragma unroll 8
    for (int n = 0; n < 256; ++n) s += fabsf(p[n * 256]);
    inv[idx] = 1.f / fmaxf(s, 1e-12f);
}

// ---------------- fp32 -> split planes ----------------
__global__ __launch_bounds__(256) void split_mat(const float* __restrict__ X,
                                                 short* __restrict__ H,
                                                 short* __restrict__ L, long long n4)
{
    long long i = (long long)blockIdx.x * 256 + threadIdx.x;
    long long stride = (long long)gridDim.x * 256;
    for (; i < n4; i += stride) {
        float4 v = ((const float4*)X)[i];
        short4 h, l;
        cvt4(v, h, l);
        ((short4*)H)[i] = h;
        ((short4*)L)[i] = l;
    }
}

// ---------------- weight slice -> transposed split planes ----------------
__global__ __launch_bounds__(256) void wsplit_t(const float* __restrict__ W, int ldw, int c0,
                                                short* __restrict__ H, short* __restrict__ L,
                                                int K)
{
    __shared__ float tile[32][33];
    int kt = blockIdx.x * 32, ct = blockIdx.y * 32;
    int tx = threadIdx.x & 31, ty = threadIdx.x >> 5;
    #pragma unroll
    for (int i = 0; i < 4; ++i)
        tile[ty + 8 * i][tx] = W[(long long)(kt + ty + 8 * i) * ldw + c0 + ct + tx];
    __syncthreads();
    #pragma unroll
    for (int i = 0; i < 4; ++i) {
        int nn = ty + 8 * i, kk = tx;
        float v = tile[kk][nn];
        short h, l;
        split1(v, h, l);
        long long o = (long long)(ct + nn) * K + kt + kk;
        H[o] = h; L[o] = l;
    }
}

// =====================================================================
// DMA split-bf16 MFMA GEMM: C = epi( A[M,K] @ B^T ) with both operands as
// transposed split planes (A:[M][K], B:[N][K]). global_load_lds(16B)
// staging into chunked LDS: plane tile = 8 chunks of (16 rows x 32 k),
// slot s <-> (m=s&15, h=s>>4); frag read = linear b128 (conflict-free).
// OM: 0 = fp32 store, 1 = split store, 2 = split accumulate.
// =====================================================================
template <int OM>
__global__ __launch_bounds__(256, 2) void gemm_dma(
    const short* __restrict__ Ah_, const short* __restrict__ Al_,
    const short* __restrict__ Bh_, const short* __restrict__ Bl_,
    int K,
    float* __restrict__ Cf, short* __restrict__ Ch, short* __restrict__ Cl, int ldC,
    const float* __restrict__ bias, int relu)
{
    __shared__ short lds[4 * 4096];   // Ah | Al | Bh | Bl, 8KB each
    short* AhS = lds;
    short* AlS = lds + 4096;
    short* BhS = lds + 8192;
    short* BlS = lds + 12288;

    const int tid = threadIdx.x;
    const int wave = tid >> 6, L = tid & 63;
    const int m0 = blockIdx.y * 128, n0 = blockIdx.x * 128;
    const int wm = (wave & 1) * 64, wn = (wave >> 1) * 64;

    // per-lane fetch coordinates within a chunk
    const int lm = L & 15;          // row within chunk
    const int lh = (L >> 4) * 8;    // k offset (shorts)

    f32x4 acc[4][4];
    #pragma unroll
    for (int i = 0; i < 4; ++i)
        #pragma unroll
        for (int j = 0; j < 4; ++j)
            acc[i][j] = (f32x4){0.f, 0.f, 0.f, 0.f};

    const int c0 = wave * 2;   // this wave's chunk pair

    for (int k0 = 0; k0 < K; k0 += 32) {
        __syncthreads();   // previous MFMA done reading LDS
        #pragma unroll
        for (int c = 0; c < 2; ++c) {
            const int chunk = c0 + c;
            const long long ga = (long long)(m0 + chunk * 16 + lm) * K + k0 + lh;
            const long long gb = (long long)(n0 + chunk * 16 + lm) * K + k0 + lh;
            GLDS(Ah_ + ga, AhS + chunk * 512);
            GLDS(Al_ + ga, AlS + chunk * 512);
            GLDS(Bh_ + gb, BhS + chunk * 512);
            GLDS(Bl_ + gb, BlS + chunk * 512);
        }
        __syncthreads();   // drains vmcnt -> LDS valid

        short8 AF[4], ALF[4], BF[4], BLF[4];
        const int ab = (wm >> 4) * 512 + L * 8;
        const int bb = (wn >> 4) * 512 + L * 8;
        #pragma unroll
        for (int t = 0; t < 4; ++t) {
            AF[t]  = *(const short8*)(AhS + ab + t * 512);
            ALF[t] = *(const short8*)(AlS + ab + t * 512);
            BF[t]  = *(const short8*)(BhS + bb + t * 512);
            BLF[t] = *(const short8*)(BlS + bb + t * 512);
        }
        #pragma unroll
        for (int ti = 0; ti < 4; ++ti)
            #pragma unroll
            for (int tj = 0; tj < 4; ++tj) {
                acc[ti][tj] = __builtin_amdgcn_mfma_f32_16x16x32_bf16(AF[ti],  BF[tj],  acc[ti][tj], 0, 0, 0);
                acc[ti][tj] = __builtin_amdgcn_mfma_f32_16x16x32_bf16(AF[ti],  BLF[tj], acc[ti][tj], 0, 0, 0);
                acc[ti][tj] = __builtin_amdgcn_mfma_f32_16x16x32_bf16(ALF[ti], BF[tj],  acc[ti][tj], 0, 0, 0);
            }
    }

    // ---- epilogue: C/D layout col = lane&15, row = (lane>>4)*4 + reg ----
    const int lcol = L & 15, lrow = (L >> 4) * 4;
    float bv[4];
    #pragma unroll
    for (int tj = 0; tj < 4; ++tj)
        bv[tj] = bias ? bias[n0 + wn + tj * 16 + lcol] : 0.f;

    #pragma unroll
    for (int ti = 0; ti < 4; ++ti) {
        #pragma unroll
        for (int r = 0; r < 4; ++r) {
            int grow = m0 + wm + ti * 16 + lrow + r;
            #pragma unroll
            for (int tj = 0; tj < 4; ++tj) {
                int gcol = n0 + wn + tj * 16 + lcol;
                float v = acc[ti][tj][r] + bv[tj];
                if (relu) v = fmaxf(v, 0.f);
                long long idx = (long long)grow * ldC + gcol;
                if (OM == 0) {
                    Cf[idx] = v;
                } else {
                    if (OM == 2) v += bf2f(Ch[idx]) + bf2f(Cl[idx]);
                    short hh, ll;
                    split1(v, hh, ll);
                    Ch[idx] = hh;
                    Cl[idx] = ll;
                }
            }
        }
    }
}

// =====================================================================
// In-kernel-convert variant (B fp32 [K][NB]) — round-5 proven; only used
// for the two new1@Wc GEMMs where p occupies the d_out weight scratch.
// =====================================================================
#define RS 36

template <int OM>
__global__ __launch_bounds__(256, 2) void gemm_cvt(
    const short* __restrict__ Ah_, const short* __restrict__ Al_,
    const float* __restrict__ Bf_, int K, int NB,
    short* __restrict__ Ch, short* __restrict__ Cl, int ldC,
    const float* __restrict__ bias)
{
    __shared__ short AhS[128 * RS];
    __shared__ short AlS[128 * RS];
    __shared__ short BhS[128 * RS];
    __shared__ short BlS[128 * RS];

    const int tid = threadIdx.x;
    const int wave = tid >> 6, L = tid & 63;
    const int m0 = blockIdx.y * 128, n0 = blockIdx.x * 128;
    const int wm = (wave & 1) * 64, wn = (wave >> 1) * 64;

    const int row = tid & 127;
    const int h16 = (tid >> 7) * 16;

    const short* ap_h = Ah_ + (long long)(m0 + row) * K + h16;
    const short* ap_l = Al_ + (long long)(m0 + row) * K + h16;

    const int bn  = tid & 127;
    const int bkb = (tid >> 7) * 4;
    const float* bf0 = Bf_ + (long long)bkb * NB + n0 + bn;

    f32x4 acc[4][4];
    #pragma unroll
    for (int i = 0; i < 4; ++i)
        #pragma unroll
        for (int j = 0; j < 4; ++j)
            acc[i][j] = (f32x4){0.f, 0.f, 0.f, 0.f};

    short8 pah[2], pal[2];
    float braw[16];
    short4 bh4[4], bl4[4];

    #pragma unroll
    for (int j = 0; j < 2; ++j) {
        pah[j] = *(const short8*)(ap_h + j * 8);
        pal[j] = *(const short8*)(ap_l + j * 8);
    }
    #pragma unroll
    for (int g = 0; g < 4; ++g)
        #pragma unroll
        for (int i = 0; i < 4; ++i)
            braw[g * 4 + i] = bf0[(long long)(g * 8 + i) * NB];
    #pragma unroll
    for (int g = 0; g < 4; ++g) {
        float4 v = {braw[g * 4 + 0], braw[g * 4 + 1], braw[g * 4 + 2], braw[g * 4 + 3]};
        cvt4(v, bh4[g], bl4[g]);
    }

    for (int k0 = 0; k0 < K; k0 += 32) {
        __syncthreads();
        #pragma unroll
        for (int j = 0; j < 2; ++j) {
            *(short4*)&AhS[row * RS + h16 + j * 8 + 0] = *(((const short4*)&pah[j]) + 0);
            *(short4*)&AhS[row * RS + h16 + j * 8 + 4] = *(((const short4*)&pah[j]) + 1);
            *(short4*)&AlS[row * RS + h16 + j * 8 + 0] = *(((const short4*)&pal[j]) + 0);
            *(short4*)&AlS[row * RS + h16 + j * 8 + 4] = *(((const short4*)&pal[j]) + 1);
        }
        #pragma unroll
        for (int g = 0; g < 4; ++g) {
            *(short4*)&BhS[bn * RS + bkb + g * 8] = bh4[g];
            *(short4*)&BlS[bn * RS + bkb + g * 8] = bl4[g];
        }
        __syncthreads();

        const bool more = (k0 + 32) < K;
        if (more) {
            #pragma unroll
            for (int j = 0; j < 2; ++j) {
                pah[j] = *(const short8*)(ap_h + k0 + 32 + j * 8);
                pal[j] = *(const short8*)(ap_l + k0 + 32 + j * 8);
            }
            const float* bp = bf0 + (long long)(k0 + 32) * NB;
            #pragma unroll
            for (int g = 0; g < 4; ++g)
                #pragma unroll
                for (int i = 0; i < 4; ++i)
                    braw[g * 4 + i] = bp[(long long)(g * 8 + i) * NB];
        }

        short8 AF[4], ALF[4], BF[4], BLF[4];
        {
            int mb = (wm + (L & 15)) * RS + (L >> 4) * 8;
            int nb = (wn + (L & 15)) * RS + (L >> 4) * 8;
            #pragma unroll
            for (int t = 0; t < 4; ++t) {
                int ao = mb + t * 16 * RS;
                *(short4*)&AF[t]        = *(short4*)&AhS[ao];
                *((short4*)&AF[t] + 1)  = *(short4*)&AhS[ao + 4];
                *(short4*)&ALF[t]       = *(short4*)&AlS[ao];
                *((short4*)&ALF[t] + 1) = *(short4*)&AlS[ao + 4];
                int bo = nb + t * 16 * RS;
                *(short4*)&BF[t]        = *(short4*)&BhS[bo];
                *((short4*)&BF[t] + 1)  = *(short4*)&BhS[bo + 4];
                *(short4*)&BLF[t]       = *(short4*)&BlS[bo];
                *((short4*)&BLF[t] + 1) = *(short4*)&BlS[bo + 4];
            }
        }
        #pragma unroll
        for (int ti = 0; ti < 4; ++ti)
            #pragma unroll
            for (int tj = 0; tj < 4; ++tj) {
                acc[ti][tj] = __builtin_amdgcn_mfma_f32_16x16x32_bf16(AF[ti],  BF[tj],  acc[ti][tj], 0, 0, 0);
                acc[ti][tj] = __builtin_amdgcn_mfma_f32_16x16x32_bf16(AF[ti],  BLF[tj], acc[ti][tj], 0, 0, 0);
                acc[ti][tj] = __builtin_amdgcn_mfma_f32_16x16x32_bf16(ALF[ti], BF[tj],  acc[ti][tj], 0, 0, 0);
            }

        if (more) {
            #pragma unroll
            for (int g = 0; g < 4; ++g) {
                float4 v = {braw[g * 4 + 0], braw[g * 4 + 1], braw[g * 4 + 2], braw[g * 4 + 3]};
                cvt4(v, bh4[g], bl4[g]);
            }
        }
    }

    const int lcol = L & 15, lrow = (L >> 4) * 4;
    float bv[4];
    #pragma unroll
    for (int tj = 0; tj < 4; ++tj)
        bv[tj] = bias ? bias[n0 + wn + tj * 16 + lcol] : 0.f;

    #pragma unroll
    for (int ti = 0; ti < 4; ++ti) {
        #pragma unroll
        for (int r = 0; r < 4; ++r) {
            int grow = m0 + wm + ti * 16 + lrow + r;
            #pragma unroll
            for (int tj = 0; tj < 4; ++tj) {
                int gcol = n0 + wn + tj * 16 + lcol;
                float v = acc[ti][tj][r] + bv[tj];
                long long idx = (long long)grow * ldC + gcol;
                if (OM == 2) v += bf2f(Ch[idx]) + bf2f(Cl[idx]);
                short hh, ll;
                split1(v, hh, ll);
                Ch[idx] = hh;
                Cl[idx] = ll;
            }
        }
    }
}

// ---------------- batched fp32 VALU GEMM (256x2048x256 per batch) ----------------
template <bool TA, bool ACC>
__global__ __launch_bounds__(256, 2) void bgemm(
    const float* __restrict__ A,
    const short* __restrict__ Bh_, const short* __restrict__ Bl_,
    short* __restrict__ Ch, short* __restrict__ Cl,
    const float* __restrict__ colscale)
{
    __shared__ float As[16][132];
    __shared__ float Bs[16][132];

    const int N = 2048;
    const long long sB = 524288;
    int z = blockIdx.z;
    const float* Az = A + (long long)z * 65536;
    const float* cs = colscale ? colscale + z * 256 : nullptr;

    int n0 = blockIdx.x * 128, m0 = blockIdx.y * 128;
    int tid = threadIdx.x;
    int tx = tid & 15, ty = tid >> 4;

    float accv[8][8];
    #pragma unroll
    for (int i = 0; i < 8; ++i)
        #pragma unroll
        for (int j = 0; j < 8; ++j) accv[i][j] = 0.f;

    for (int k0 = 0; k0 < 256; k0 += 16) {
        if (!TA) {
            #pragma unroll
            for (int i = 0; i < 2; ++i) {
                int lin = tid + i * 256;
                int r  = lin >> 2;
                int c4 = (lin & 3) * 4;
                float4 v = *(const float4*)(Az + (long long)(m0 + r) * 256 + k0 + c4);
                if (cs) {
                    v.x *= cs[k0 + c4 + 0]; v.y *= cs[k0 + c4 + 1];
                    v.z *= cs[k0 + c4 + 2]; v.w *= cs[k0 + c4 + 3];
                }
                As[c4 + 0][r] = v.x; As[c4 + 1][r] = v.y;
                As[c4 + 2][r] = v.z; As[c4 + 3][r] = v.w;
            }
        } else {
            #pragma unroll
            for (int i = 0; i < 2; ++i) {
                int lin = tid + i * 256;
                int kk = lin >> 5;
                int m4 = (lin & 31) * 4;
                *(float4*)&As[kk][m4] =
                    *(const float4*)(Az + (long long)(k0 + kk) * 256 + m0 + m4);
            }
        }
        #pragma unroll
        for (int i = 0; i < 2; ++i) {
            int lin = tid + i * 256;
            int kk = lin >> 5;
            int n4 = (lin & 31) * 4;
            long long off = (long long)z * sB + (long long)(k0 + kk) * N + n0 + n4;
            short4 h = *(const short4*)(Bh_ + off);
            short4 l = *(const short4*)(Bl_ + off);
            Bs[kk][n4 + 0] = bf2f(h.x) + bf2f(l.x);
            Bs[kk][n4 + 1] = bf2f(h.y) + bf2f(l.y);
            Bs[kk][n4 + 2] = bf2f(h.z) + bf2f(l.z);
            Bs[kk][n4 + 3] = bf2f(h.w) + bf2f(l.w);
        }
        __syncthreads();

        #pragma unroll
        for (int kk = 0; kk < 16; ++kk) {
            float a[8], b[8];
            *(float4*)&a[0] = *(const float4*)&As[kk][ty * 8];
            *(float4*)&a[4] = *(const float4*)&As[kk][ty * 8 + 4];
            *(float4*)&b[0] = *(const float4*)&Bs[kk][tx * 8];
            *(float4*)&b[4] = *(const float4*)&Bs[kk][tx * 8 + 4];
            #pragma unroll
            for (int i = 0; i < 8; ++i)
                #pragma unroll
                for (int j = 0; j < 8; ++j)
                    accv[i][j] = fmaf(a[i], b[j], accv[i][j]);
        }
        __syncthreads();
    }

    #pragma unroll
    for (int i = 0; i < 8; ++i) {
        int rowl = m0 + ty * 8 + i;
        long long base = (long long)z * sB + (long long)rowl * N;
        #pragma unroll
        for (int j = 0; j < 8; ++j) {
            int col = n0 + tx * 8 + j;
            long long idx = base + col;
            float v = accv[i][j];
            if (ACC) v += bf2f(Ch[idx]) + bf2f(Cl[idx]);
            short hh, ll;
            split1(v, hh, ll);
            Ch[idx] = hh;
            Cl[idx] = ll;
        }
    }
}

// ---------------- fp64-accumulate affinity GEMM ----------------
__global__ __launch_bounds__(256) void gemm_bt_f64(
    const float* __restrict__ A,
    const short* __restrict__ Bh_, const short* __restrict__ Bl_,
    float* __restrict__ C)
{
    __shared__ float As[16][65];
    __shared__ float Bs[16][65];

    const int K = 2048;
    int z = blockIdx.z;
    const float* Az = A + (long long)z * 524288;
    C += (long long)z * 65536;

    int n0 = blockIdx.x * 64;
    int m0 = blockIdx.y * 64;
    int tid = threadIdx.x;
    int tx = tid & 15;
    int ty = tid >> 4;

    double acc[4][4];
    #pragma unroll
    for (int i = 0; i < 4; ++i)
        #pragma unroll
        for (int j = 0; j < 4; ++j) acc[i][j] = 0.0;

    int r  = tid >> 2;
    int c4 = (tid & 3) * 4;

    for (int k0 = 0; k0 < K; k0 += 16) {
        {
            const float4 v = *(const float4*)(Az + (long long)(m0 + r) * K + k0 + c4);
            As[c4 + 0][r] = v.x; As[c4 + 1][r] = v.y;
            As[c4 + 2][r] = v.z; As[c4 + 3][r] = v.w;
        }
        {
            long long off = (long long)z * 524288 + (long long)(n0 + r) * K + k0 + c4;
            short4 h = *(const short4*)(Bh_ + off);
            short4 l = *(const short4*)(Bl_ + off);
            Bs[c4 + 0][r] = bf2f(h.x) + bf2f(l.x);
            Bs[c4 + 1][r] = bf2f(h.y) + bf2f(l.y);
            Bs[c4 + 2][r] = bf2f(h.z) + bf2f(l.z);
            Bs[c4 + 3][r] = bf2f(h.w) + bf2f(l.w);
        }
        __syncthreads();

        #pragma unroll
        for (int kk = 0; kk < 16; ++kk) {
            double a[4], b[4];
            #pragma unroll
            for (int i = 0; i < 4; ++i) a[i] = (double)As[kk][ty + 16 * i];
            #pragma unroll
            for (int j = 0; j < 4; ++j) b[j] = (double)Bs[kk][tx + 16 * j];
            #pragma unroll
            for (int i = 0; i < 4; ++i)
                #pragma unroll
                for (int j = 0; j < 4; ++j)
                    acc[i][j] = fma(a[i], b[j], acc[i][j]);
        }
        __syncthreads();
    }

    #pragma unroll
    for (int i = 0; i < 4; ++i) {
        int rowl = m0 + ty + 16 * i;
        #pragma unroll
        for (int j = 0; j < 4; ++j)
            C[(long long)rowl * 256 + n0 + tx + 16 * j] = (float)acc[i][j];
    }
}

// ---------------- Sinkhorn ----------------
__global__ __launch_bounds__(256) void sk_row(float* __restrict__ S,
                                              const int* __restrict__ n1, int init)
{
    int r = blockIdx.x * 4 + (threadIdx.x >> 6);
    int lane = threadIdx.x & 63;
    int b = r >> 8, n = r & 255;
    float* p = S + (long long)r * 256;
    int lim = n1[b];
    if (n >= lim) {
        float4 neg = {NEGV, NEGV, NEGV, NEGV};
        *(float4*)(p + lane * 4) = neg;
        return;
    }
    float4 v = *(const float4*)(p + lane * 4);
    if (init) {
        v.x /= SK_TAU; v.y /= SK_TAU; v.z /= SK_TAU; v.w /= SK_TAU;
    }
    float m = fmaxf(fmaxf(v.x, v.y), fmaxf(v.z, v.w));
    #pragma unroll
    for (int off = 1; off < 64; off <<= 1) m = fmaxf(m, __shfl_xor(m, off));
    float s = expf(v.x - m) + expf(v.y - m) + expf(v.z - m) + expf(v.w - m);
    #pragma unroll
    for (int off = 1; off < 64; off <<= 1) s += __shfl_xor(s, off);
    float lse = m + logf(s);
    v.x -= lse; v.y -= lse; v.z -= lse; v.w -= lse;
    *(float4*)(p + lane * 4) = v;
}

__global__ __launch_bounds__(64) void sk_col(float* __restrict__ S,
                                             const int* __restrict__ n1, int final_)
{
    int b = blockIdx.y;
    int m = blockIdx.x * 64 + threadIdx.x;
    float* base = S + (long long)b * 65536;
    int lim = n1[b];
    float mx = -3.4e38f, sum = 0.f;
    for (int n = 0; n < 256; ++n) {
        float x = base[n * 256 + m];
        float nm = fmaxf(mx, x);
        sum = sum * expf(mx - nm) + expf(x - nm);
        mx = nm;
    }
    float lse = mx + logf(sum);
    if (final_) {
        for (int n = 0; n < 256; ++n) {
            float x = base[n * 256 + m];
            base[n * 256 + m] = (n < lim) ? expf(x - lse) : 0.f;
        }
    } else {
        for (int n = 0; n < 256; ++n) {
            float x = base[n * 256 + m];
            base[n * 256 + m] = (n < lim) ? (x - lse) : NEGV;
        }
    }
}

static void sinkhorn(hipStream_t st, float* S, const int* n1)
{
    sk_row<<<2048, 256, 0, st>>>(S, n1, 1);
    for (int it = 1; it < 10; ++it) {
        if (it & 1)
            sk_col<<<dim3(4, 32), 64, 0, st>>>(S, n1, it == 9);
        else
            sk_row<<<2048, 256, 0, st>>>(S, n1, 0);
    }
}

// ---------------- launch wrappers ----------------
static void gsp(hipStream_t st, int om, const short* Ah, const short* Al,
                const short* Bh, const short* Bl, int Ns, int K,
                float* Cf, short* Ch, short* Cl, const float* bias, int relu)
{
    dim3 grid(Ns / 128, 64), block(256);
    if (om == 0)
        gemm_dma<0><<<grid, block, 0, st>>>(Ah, Al, Bh, Bl, K, Cf, nullptr, nullptr, 2048, bias, relu);
    else if (om == 1)
        gemm_dma<1><<<grid, block, 0, st>>>(Ah, Al, Bh, Bl, K, nullptr, Ch, Cl, 2048, bias, relu);
    else
        gemm_dma<2><<<grid, block, 0, st>>>(Ah, Al, Bh, Bl, K, nullptr, Ch, Cl, 2048, bias, relu);
}

static void gsc(hipStream_t st, int om, const short* Ah, const short* Al,
                const float* Bf, short* Ch, short* Cl, const float* bias)
{
    dim3 grid(16, 64), block(256);
    if (om == 1)
        gemm_cvt<1><<<grid, block, 0, st>>>(Ah, Al, Bf, 2048, 2048, Ch, Cl, 2048, bias);
    else
        gemm_cvt<2><<<grid, block, 0, st>>>(Ah, Al, Bf, 2048, 2048, Ch, Cl, 2048, bias);
}

static void wsp(hipStream_t st, const float* W, int Krows, int c0, int ncols,
                short* H, short* L)
{
    dim3 grid(Krows / 32, ncols / 32);
    wsplit_t<<<grid, 256, 0, st>>>(W, 2048, c0, H, L, Krows);
}

// ---------------- driver ----------------
extern "C" void kernel_launch(void* const* d_in, const int* in_sizes, int n_in,
                              void* d_out, int out_size, void* d_ws, size_t ws_size,
                              hipStream_t stream)
{
    const float* feat1 = (const float*)d_in[0];
    const float* feat2 = (const float*)d_in[1];
    const float* A1    = (const float*)d_in[2];
    const float* A2    = (const float*)d_in[3];
    const int*   n1    = (const int*)d_in[4];
    const float* W0a = (const float*)d_in[8];  const float* b0a = (const float*)d_in[9];
    const float* W0u = (const float*)d_in[10]; const float* b0u = (const float*)d_in[11];
    const float* W1a = (const float*)d_in[12]; const float* b1a = (const float*)d_in[13];
    const float* W1u = (const float*)d_in[14]; const float* b1u = (const float*)d_in[15];
    const float* Wc  = (const float*)d_in[16]; const float* bc  = (const float*)d_in[17];
    const float* Aaff0 = (const float*)d_in[18];
    const float* Aaff1 = (const float*)d_in[19];

    const long long TSZ = 16777216LL;
    const long long PL  = 16777216LL;
    const long long PF  = 8388608LL;

    float* T1f = (float*)d_ws;
    float* T2f = T1f + TSZ;
    float* T3f = T2f + TSZ;
    float* T4f = T3f + TSZ;
    short *T1h = (short*)T1f, *T1l = T1h + PL;
    short *T2h = (short*)T2f, *T2l = T2h + PL;
    short *T3h = (short*)T3f, *T3l = T3h + PL;
    short *T4h = (short*)T4f, *T4l = T4h + PL;

    short* f1h = (short*)T4f;      short* f1l = f1h + PF;
    short* f2h = f1h + 2 * PF;     short* f2l = f1h + 3 * PF;
    float* invA = (float*)T4f;
    float* invB = invA + 8192;

    float* S   = (float*)d_out;
    short* swh = (short*)d_out;
    short* swl = swh + 2097152;
    float* inv1 = S;
    float* inv2 = S + 8192;

    dim3 bgrid(16, 2, 32), bblk(256);

    // ===== Phase 0: split feats =====
    split_mat<<<2048, 256, 0, stream>>>(feat1, f1h, f1l, 8192LL * 1024 / 4);
    split_mat<<<2048, 256, 0, stream>>>(feat2, f2h, f2l, 8192LL * 1024 / 4);

    // ===== Phase 1: gconv layer 0 =====
    wsp(stream, W0u, 1024, 0, 2048, swh, swl);
    gsp(stream, 1, f1h, f1l, swh, swl, 2048, 1024, nullptr, T1h, T1l, b0u, 1);
    gsp(stream, 1, f2h, f2l, swh, swl, 2048, 1024, nullptr, T2h, T2l, b0u, 1);
    wsp(stream, W0a, 1024, 0, 2048, swh, swl);
    gsp(stream, 1, f1h, f1l, swh, swl, 2048, 1024, nullptr, T3h, T3l, b0a, 1);
    colnorm_k<<<32, 256, 0, stream>>>(A1, invA);
    colnorm_k<<<32, 256, 0, stream>>>(A2, invB);
    bgemm<false, true><<<bgrid, bblk, 0, stream>>>(A1, T3h, T3l, T1h, T1l, invA);
    gsp(stream, 1, f2h, f2l, swh, swl, 2048, 1024, nullptr, T3h, T3l, b0a, 1);
    bgemm<false, true><<<bgrid, bblk, 0, stream>>>(A2, T3h, T3l, T2h, T2l, invB);

    // ===== Phase 2: affinity 0 =====
    wsp(stream, Aaff0, 2048, 0, 1024, swh, swl);
    gsp(stream, 0, T1h, T1l, swh, swl, 1024, 2048, T3f + 0, nullptr, nullptr, nullptr, 0);
    wsp(stream, Aaff0, 2048, 1024, 1024, swh, swl);
    gsp(stream, 0, T1h, T1l, swh, swl, 1024, 2048, T3f + 1024, nullptr, nullptr, nullptr, 0);
    gemm_bt_f64<<<dim3(4, 4, 32), 256, 0, stream>>>(T3f, T2h, T2l, S);

    sinkhorn(stream, S, n1);

    // ===== Phase 4: cross-graph update =====
    bgemm<false, false><<<bgrid, bblk, 0, stream>>>(S, T2h, T2l, T3h, T3l, nullptr);   // c1
    gsc(stream, 1, T1h, T1l, Wc,           T4h, T4l, bc);        // new1 (p alive)
    gsc(stream, 2, T3h, T3l, Wc + 4194304, T4h, T4l, nullptr);
    bgemm<true, false><<<bgrid, bblk, 0, stream>>>(S, T1h, T1l, T3h, T3l, nullptr);    // c2; p dead
    wsp(stream, Wc, 2048, 0, 1024, swh, swl);
    gsp(stream, 1, T2h, T2l, swh, swl, 1024, 2048, nullptr, T1h + 0,    T1l + 0,    bc, 0);
    wsp(stream, Wc, 2048, 1024, 1024, swh, swl);
    gsp(stream, 1, T2h, T2l, swh, swl, 1024, 2048, nullptr, T1h + 1024, T1l + 1024, bc + 1024, 0);
    wsp(stream, Wc + 4194304, 2048, 0, 1024, swh, swl);
    gsp(stream, 2, T3h, T3l, swh, swl, 1024, 2048, nullptr, T1h + 0,    T1l + 0,    nullptr, 0);
    wsp(stream, Wc + 4194304, 2048, 1024, 1024, swh, swl);
    gsp(stream, 2, T3h, T3l, swh, swl, 1024, 2048, nullptr, T1h + 1024, T1l + 1024, nullptr, 0);

    // ===== Phase 5: gconv layer 1 =====
    wsp(stream, W1a, 2048, 0, 1024, swh, swl);
    gsp(stream, 1, T4h, T4l, swh, swl, 1024, 2048, nullptr, T2h + 0,    T2l + 0,    b1a, 1);
    wsp(stream, W1a, 2048, 1024, 1024, swh, swl);
    gsp(stream, 1, T4h, T4l, swh, swl, 1024, 2048, nullptr, T2h + 1024, T2l + 1024, b1a + 1024, 1);
    wsp(stream, W1u, 2048, 0, 1024, swh, swl);
    gsp(stream, 1, T4h, T4l, swh, swl, 1024, 2048, nullptr, T3h + 0,    T3l + 0,    b1u, 1);
    wsp(stream, W1u, 2048, 1024, 1024, swh, swl);
    gsp(stream, 1, T4h, T4l, swh, swl, 1024, 2048, nullptr, T3h + 1024, T3l + 1024, b1u + 1024, 1);
    colnorm_k<<<32, 256, 0, stream>>>(A1, inv1);
    bgemm<false, true><<<bgrid, bblk, 0, stream>>>(A1, T2h, T2l, T3h, T3l, inv1);
    wsp(stream, W1a, 2048, 0, 1024, swh, swl);
    gsp(stream, 1, T1h, T1l, swh, swl, 1024, 2048, nullptr, T2h + 0,    T2l + 0,    b1a, 1);
    wsp(stream, W1a, 2048, 1024, 1024, swh, swl);
    gsp(stream, 1, T1h, T1l, swh, swl, 1024, 2048, nullptr, T2h + 1024, T2l + 1024, b1a + 1024, 1);
    wsp(stream, W1u, 2048, 0, 1024, swh, swl);
    gsp(stream, 1, T1h, T1l, swh, swl, 1024, 2048, nullptr, T4h + 0,    T4l + 0,    b1u, 1);
    wsp(stream, W1u, 2048, 1024, 1024, swh, swl);
    gsp(stream, 1, T1h, T1l, swh, swl, 1024, 2048, nullptr, T4h + 1024, T4l + 1024, b1u + 1024, 1);
    colnorm_k<<<32, 256, 0, stream>>>(A2, inv2);
    bgemm<false, true><<<bgrid, bblk, 0, stream>>>(A2, T2h, T2l, T4h, T4l, inv2);

    // ===== Phase 6: affinity 1 =====
    wsp(stream, Aaff1, 2048, 0, 1024, swh, swl);
    gsp(stream, 0, T3h, T3l, swh, swl, 1024, 2048, T1f + 0, nullptr, nullptr, nullptr, 0);
    wsp(stream, Aaff1, 2048, 1024, 1024, swh, swl);
    gsp(stream, 0, T3h, T3l, swh, swl, 1024, 2048, T1f + 1024, nullptr, nullptr, nullptr, 0);
    gemm_bt_f64<<<dim3(4, 4, 32), 256, 0, stream>>>(T1f, T4h, T4l, S);

    sinkhorn(stream, S, n1);
}

// Round 7
// 5249.349 us; speedup vs baseline: 1.1250x; 1.0496x over previous
//
#include <hip/hip_runtime.h>
#include <math.h>

#define NEGV -1e9f
#define SK_TAU 0.05f

typedef __attribute__((ext_vector_type(4))) float f32x4;
typedef __attribute__((ext_vector_type(8))) short short8;

#define GLDS(g, l) __builtin_amdgcn_global_load_lds( \
    (const __attribute__((address_space(1))) void*)(g), \
    (__attribute__((address_space(3))) void*)(l), 16, 0, 0)

// ---------------- bf16 split helpers ----------------
__device__ inline unsigned bf16rtn(float x) {
    unsigned u = __float_as_uint(x);
    return (u + 0x7FFFu + ((u >> 16) & 1u)) >> 16;
}
__device__ inline float bf2f(short h) {
    return __uint_as_float(((unsigned)(unsigned short)h) << 16);
}
__device__ inline void split1(float x, short& h, short& l) {
    unsigned hu = bf16rtn(x);
    h = (short)hu;
    float r = x - __uint_as_float(hu << 16);
    l = (short)(__float_as_uint(r) >> 16);
}
__device__ inline void cvt4(const float4 v, short4& h, short4& l) {
    unsigned h0 = bf16rtn(v.x), h1 = bf16rtn(v.y), h2 = bf16rtn(v.z), h3 = bf16rtn(v.w);
    h.x = (short)h0; h.y = (short)h1; h.z = (short)h2; h.w = (short)h3;
    float l0 = v.x - __uint_as_float(h0 << 16);
    float l1 = v.y - __uint_as_float(h1 << 16);
    float l2 = v.z - __uint_as_float(h2 << 16);
    float l3 = v.w - __uint_as_float(h3 << 16);
    l.x = (short)(__float_as_uint(l0) >> 16);
    l.y = (short)(__float_as_uint(l1) >> 16);
    l.z = (short)(__float_as_uint(l2) >> 16);
    l.w = (short)(__float_as_uint(l3) >> 16);
}

// ---------------- inv column L1 norm ----------------
__global__ __launch_bounds__(256) void colnorm_k(const float* __restrict__ A,
                                                 float* __restrict__ inv)
{
    int idx = blockIdx.x * 256 + threadIdx.x;
    int b = idx >> 8, m = idx & 255;
    const float* p = A + (long long)b * 65536 + m;
    float s = 0.f;
    #pragma unroll 8
    for (int n = 0; n < 256; ++n) s += fabsf(p[n * 256]);
    inv[idx] = 1.f / fmaxf(s, 1e-12f);
}

// ---------------- fp32 -> split planes ----------------
__global__ __launch_bounds__(256) void split_mat(const float* __restrict__ X,
                                                 short* __restrict__ H,
                                                 short* __restrict__ L, long long n4)
{
    long long i = (long long)blockIdx.x * 256 + threadIdx.x;
    long long stride = (long long)gridDim.x * 256;
    for (; i < n4; i += stride) {
        float4 v = ((const float4*)X)[i];
        short4 h, l;
        cvt4(v, h, l);
        ((short4*)H)[i] = h;
        ((short4*)L)[i] = l;
    }
}

// ---------------- weight slice -> transposed split planes ----------------
__global__ __launch_bounds__(256) void wsplit_t(const float* __restrict__ W, int ldw, int c0,
                                                short* __restrict__ H, short* __restrict__ L,
                                                int K)
{
    __shared__ float tile[32][33];
    int kt = blockIdx.x * 32, ct = blockIdx.y * 32;
    int tx = threadIdx.x & 31, ty = threadIdx.x >> 5;
    #pragma unroll
    for (int i = 0; i < 4; ++i)
        tile[ty + 8 * i][tx] = W[(long long)(kt + ty + 8 * i) * ldw + c0 + ct + tx];
    __syncthreads();
    #pragma unroll
    for (int i = 0; i < 4; ++i) {
        int nn = ty + 8 * i, kk = tx;
        float v = tile[kk][nn];
        short h, l;
        split1(v, h, l);
        long long o = (long long)(ct + nn) * K + kt + kk;
        H[o] = h; L[o] = l;
    }
}

// =====================================================================
// DMA split-bf16 MFMA GEMM, depth-2 double-buffered.
// C = epi( A[M,K] @ B^T ); A:[M][K] planes, B:[N][K] planes.
// Per panel: barrier (drains DMA of current panel, issued last iter);
// issue DMA for next panel into the other buffer; ds_read + 48 MFMA.
// Chunked LDS: tile = 8 chunks of (16 rows x 32 k); frag read = linear b128.
// OM: 0 = fp32 store, 1 = split store, 2 = split accumulate.
// =====================================================================
template <int OM>
__global__ __launch_bounds__(256, 2) void gemm_dma(
    const short* __restrict__ Ah_, const short* __restrict__ Al_,
    const short* __restrict__ Bh_, const short* __restrict__ Bl_,
    int K,
    float* __restrict__ Cf, short* __restrict__ Ch, short* __restrict__ Cl, int ldC,
    const float* __restrict__ bias, int relu)
{
    __shared__ short lds[2][16384];   // [buf][Ah|Al|Bh|Bl x 4096], 32 KB each

    const int tid = threadIdx.x;
    const int wave = tid >> 6, L = tid & 63;
    const int m0 = blockIdx.y * 128, n0 = blockIdx.x * 128;
    const int wm = (wave & 1) * 64, wn = (wave >> 1) * 64;

    const int lm = L & 15;
    const int lh = (L >> 4) * 8;
    const int c0 = wave * 2;

    long long ga[2], gb[2];
    #pragma unroll
    for (int c = 0; c < 2; ++c) {
        ga[c] = (long long)(m0 + (c0 + c) * 16 + lm) * K + lh;
        gb[c] = (long long)(n0 + (c0 + c) * 16 + lm) * K + lh;
    }

    f32x4 acc[4][4];
    #pragma unroll
    for (int i = 0; i < 4; ++i)
        #pragma unroll
        for (int j = 0; j < 4; ++j)
            acc[i][j] = (f32x4){0.f, 0.f, 0.f, 0.f};

    // prologue: panel 0 -> buf 0
    #pragma unroll
    for (int c = 0; c < 2; ++c) {
        const int sl = (c0 + c) * 512;
        GLDS(Ah_ + ga[c], lds[0] + sl);
        GLDS(Al_ + ga[c], lds[0] + 4096 + sl);
        GLDS(Bh_ + gb[c], lds[0] + 8192 + sl);
        GLDS(Bl_ + gb[c], lds[0] + 12288 + sl);
    }

    int cur = 0;
    for (int k0 = 0; k0 < K; k0 += 32) {
        __syncthreads();   // drains vmcnt: DMA into lds[cur] complete; prev reads of lds[1-cur] done

        if (k0 + 32 < K) {
            short* nb = lds[1 - cur];
            #pragma unroll
            for (int c = 0; c < 2; ++c) {
                const int sl = (c0 + c) * 512;
                GLDS(Ah_ + ga[c] + k0 + 32, nb + sl);
                GLDS(Al_ + ga[c] + k0 + 32, nb + 4096 + sl);
                GLDS(Bh_ + gb[c] + k0 + 32, nb + 8192 + sl);
                GLDS(Bl_ + gb[c] + k0 + 32, nb + 12288 + sl);
            }
        }

        const short* AhS = lds[cur];
        const short* AlS = lds[cur] + 4096;
        const short* BhS = lds[cur] + 8192;
        const short* BlS = lds[cur] + 12288;

        short8 AF[4], ALF[4], BF[4], BLF[4];
        const int ab = (wm >> 4) * 512 + L * 8;
        const int bb = (wn >> 4) * 512 + L * 8;
        #pragma unroll
        for (int t = 0; t < 4; ++t) {
            AF[t]  = *(const short8*)(AhS + ab + t * 512);
            ALF[t] = *(const short8*)(AlS + ab + t * 512);
            BF[t]  = *(const short8*)(BhS + bb + t * 512);
            BLF[t] = *(const short8*)(BlS + bb + t * 512);
        }
        #pragma unroll
        for (int ti = 0; ti < 4; ++ti)
            #pragma unroll
            for (int tj = 0; tj < 4; ++tj) {
                acc[ti][tj] = __builtin_amdgcn_mfma_f32_16x16x32_bf16(AF[ti],  BF[tj],  acc[ti][tj], 0, 0, 0);
                acc[ti][tj] = __builtin_amdgcn_mfma_f32_16x16x32_bf16(AF[ti],  BLF[tj], acc[ti][tj], 0, 0, 0);
                acc[ti][tj] = __builtin_amdgcn_mfma_f32_16x16x32_bf16(ALF[ti], BF[tj],  acc[ti][tj], 0, 0, 0);
            }
        cur ^= 1;
    }

    // ---- epilogue: C/D layout col = lane&15, row = (lane>>4)*4 + reg ----
    const int lcol = L & 15, lrow = (L >> 4) * 4;
    float bv[4];
    #pragma unroll
    for (int tj = 0; tj < 4; ++tj)
        bv[tj] = bias ? bias[n0 + wn + tj * 16 + lcol] : 0.f;

    #pragma unroll
    for (int ti = 0; ti < 4; ++ti) {
        #pragma unroll
        for (int r = 0; r < 4; ++r) {
            int grow = m0 + wm + ti * 16 + lrow + r;
            #pragma unroll
            for (int tj = 0; tj < 4; ++tj) {
                int gcol = n0 + wn + tj * 16 + lcol;
                float v = acc[ti][tj][r] + bv[tj];
                if (relu) v = fmaxf(v, 0.f);
                long long idx = (long long)grow * ldC + gcol;
                if (OM == 0) {
                    Cf[idx] = v;
                } else {
                    if (OM == 2) v += bf2f(Ch[idx]) + bf2f(Cl[idx]);
                    short hh, ll;
                    split1(v, hh, ll);
                    Ch[idx] = hh;
                    Cl[idx] = ll;
                }
            }
        }
    }
}

// =====================================================================
// In-kernel-convert variant (B fp32 [K][NB]) — used only for the two
// new1@Wc GEMMs where p occupies the d_out weight scratch.
// =====================================================================
#define RS 36

template <int OM>
__global__ __launch_bounds__(256, 2) void gemm_cvt(
    const short* __restrict__ Ah_, const short* __restrict__ Al_,
    const float* __restrict__ Bf_, int K, int NB,
    short* __restrict__ Ch, short* __restrict__ Cl, int ldC,
    const float* __restrict__ bias)
{
    __shared__ short AhS[128 * RS];
    __shared__ short AlS[128 * RS];
    __shared__ short BhS[128 * RS];
    __shared__ short BlS[128 * RS];

    const int tid = threadIdx.x;
    const int wave = tid >> 6, L = tid & 63;
    const int m0 = blockIdx.y * 128, n0 = blockIdx.x * 128;
    const int wm = (wave & 1) * 64, wn = (wave >> 1) * 64;

    const int row = tid & 127;
    const int h16 = (tid >> 7) * 16;

    const short* ap_h = Ah_ + (long long)(m0 + row) * K + h16;
    const short* ap_l = Al_ + (long long)(m0 + row) * K + h16;

    const int bn  = tid & 127;
    const int bkb = (tid >> 7) * 4;
    const float* bf0 = Bf_ + (long long)bkb * NB + n0 + bn;

    f32x4 acc[4][4];
    #pragma unroll
    for (int i = 0; i < 4; ++i)
        #pragma unroll
        for (int j = 0; j < 4; ++j)
            acc[i][j] = (f32x4){0.f, 0.f, 0.f, 0.f};

    short8 pah[2], pal[2];
    float braw[16];
    short4 bh4[4], bl4[4];

    #pragma unroll
    for (int j = 0; j < 2; ++j) {
        pah[j] = *(const short8*)(ap_h + j * 8);
        pal[j] = *(const short8*)(ap_l + j * 8);
    }
    #pragma unroll
    for (int g = 0; g < 4; ++g)
        #pragma unroll
        for (int i = 0; i < 4; ++i)
            braw[g * 4 + i] = bf0[(long long)(g * 8 + i) * NB];
    #pragma unroll
    for (int g = 0; g < 4; ++g) {
        float4 v = {braw[g * 4 + 0], braw[g * 4 + 1], braw[g * 4 + 2], braw[g * 4 + 3]};
        cvt4(v, bh4[g], bl4[g]);
    }

    for (int k0 = 0; k0 < K; k0 += 32) {
        __syncthreads();
        #pragma unroll
        for (int j = 0; j < 2; ++j) {
            *(short4*)&AhS[row * RS + h16 + j * 8 + 0] = *(((const short4*)&pah[j]) + 0);
            *(short4*)&AhS[row * RS + h16 + j * 8 + 4] = *(((const short4*)&pah[j]) + 1);
            *(short4*)&AlS[row * RS + h16 + j * 8 + 0] = *(((const short4*)&pal[j]) + 0);
            *(short4*)&AlS[row * RS + h16 + j * 8 + 4] = *(((const short4*)&pal[j]) + 1);
        }
        #pragma unroll
        for (int g = 0; g < 4; ++g) {
            *(short4*)&BhS[bn * RS + bkb + g * 8] = bh4[g];
            *(short4*)&BlS[bn * RS + bkb + g * 8] = bl4[g];
        }
        __syncthreads();

        const bool more = (k0 + 32) < K;
        if (more) {
            #pragma unroll
            for (int j = 0; j < 2; ++j) {
                pah[j] = *(const short8*)(ap_h + k0 + 32 + j * 8);
                pal[j] = *(const short8*)(ap_l + k0 + 32 + j * 8);
            }
            const float* bp = bf0 + (long long)(k0 + 32) * NB;
            #pragma unroll
            for (int g = 0; g < 4; ++g)
                #pragma unroll
                for (int i = 0; i < 4; ++i)
                    braw[g * 4 + i] = bp[(long long)(g * 8 + i) * NB];
        }

        short8 AF[4], ALF[4], BF[4], BLF[4];
        {
            int mb = (wm + (L & 15)) * RS + (L >> 4) * 8;
            int nb = (wn + (L & 15)) * RS + (L >> 4) * 8;
            #pragma unroll
            for (int t = 0; t < 4; ++t) {
                int ao = mb + t * 16 * RS;
                *(short4*)&AF[t]        = *(short4*)&AhS[ao];
                *((short4*)&AF[t] + 1)  = *(short4*)&AhS[ao + 4];
                *(short4*)&ALF[t]       = *(short4*)&AlS[ao];
                *((short4*)&ALF[t] + 1) = *(short4*)&AlS[ao + 4];
                int bo = nb + t * 16 * RS;
                *(short4*)&BF[t]        = *(short4*)&BhS[bo];
                *((short4*)&BF[t] + 1)  = *(short4*)&BhS[bo + 4];
                *(short4*)&BLF[t]       = *(short4*)&BlS[bo];
                *((short4*)&BLF[t] + 1) = *(short4*)&BlS[bo + 4];
            }
        }
        #pragma unroll
        for (int ti = 0; ti < 4; ++ti)
            #pragma unroll
            for (int tj = 0; tj < 4; ++tj) {
                acc[ti][tj] = __builtin_amdgcn_mfma_f32_16x16x32_bf16(AF[ti],  BF[tj],  acc[ti][tj], 0, 0, 0);
                acc[ti][tj] = __builtin_amdgcn_mfma_f32_16x16x32_bf16(AF[ti],  BLF[tj], acc[ti][tj], 0, 0, 0);
                acc[ti][tj] = __builtin_amdgcn_mfma_f32_16x16x32_bf16(ALF[ti], BF[tj],  acc[ti][tj], 0, 0, 0);
            }

        if (more) {
            #pragma unroll
            for (int g = 0; g < 4; ++g) {
                float4 v = {braw[g * 4 + 0], braw[g * 4 + 1], braw[g * 4 + 2], braw[g * 4 + 3]};
                cvt4(v, bh4[g], bl4[g]);
            }
        }
    }

    const int lcol = L & 15, lrow = (L >> 4) * 4;
    float bv[4];
    #pragma unroll
    for (int tj = 0; tj < 4; ++tj)
        bv[tj] = bias ? bias[n0 + wn + tj * 16 + lcol] : 0.f;

    #pragma unroll
    for (int ti = 0; ti < 4; ++ti) {
        #pragma unroll
        for (int r = 0; r < 4; ++r) {
            int grow = m0 + wm + ti * 16 + lrow + r;
            #pragma unroll
            for (int tj = 0; tj < 4; ++tj) {
                int gcol = n0 + wn + tj * 16 + lcol;
                float v = acc[ti][tj][r] + bv[tj];
                long long idx = (long long)grow * ldC + gcol;
                if (OM == 2) v += bf2f(Ch[idx]) + bf2f(Cl[idx]);
                short hh, ll;
                split1(v, hh, ll);
                Ch[idx] = hh;
                Cl[idx] = ll;
            }
        }
    }
}

// ---------------- batched fp32 VALU GEMM (256x2048x256 per batch) ----------------
template <bool TA, bool ACC>
__global__ __launch_bounds__(256, 2) void bgemm(
    const float* __restrict__ A,
    const short* __restrict__ Bh_, const short* __restrict__ Bl_,
    short* __restrict__ Ch, short* __restrict__ Cl,
    const float* __restrict__ colscale)
{
    __shared__ float As[16][132];
    __shared__ float Bs[16][132];

    const int N = 2048;
    const long long sB = 524288;
    int z = blockIdx.z;
    const float* Az = A + (long long)z * 65536;
    const float* cs = colscale ? colscale + z * 256 : nullptr;

    int n0 = blockIdx.x * 128, m0 = blockIdx.y * 128;
    int tid = threadIdx.x;
    int tx = tid & 15, ty = tid >> 4;

    float accv[8][8];
    #pragma unroll
    for (int i = 0; i < 8; ++i)
        #pragma unroll
        for (int j = 0; j < 8; ++j) accv[i][j] = 0.f;

    for (int k0 = 0; k0 < 256; k0 += 16) {
        if (!TA) {
            #pragma unroll
            for (int i = 0; i < 2; ++i) {
                int lin = tid + i * 256;
                int r  = lin >> 2;
                int c4 = (lin & 3) * 4;
                float4 v = *(const float4*)(Az + (long long)(m0 + r) * 256 + k0 + c4);
                if (cs) {
                    v.x *= cs[k0 + c4 + 0]; v.y *= cs[k0 + c4 + 1];
                    v.z *= cs[k0 + c4 + 2]; v.w *= cs[k0 + c4 + 3];
                }
                As[c4 + 0][r] = v.x; As[c4 + 1][r] = v.y;
                As[c4 + 2][r] = v.z; As[c4 + 3][r] = v.w;
            }
        } else {
            #pragma unroll
            for (int i = 0; i < 2; ++i) {
                int lin = tid + i * 256;
                int kk = lin >> 5;
                int m4 = (lin & 31) * 4;
                *(float4*)&As[kk][m4] =
                    *(const float4*)(Az + (long long)(k0 + kk) * 256 + m0 + m4);
            }
        }
        #pragma unroll
        for (int i = 0; i < 2; ++i) {
            int lin = tid + i * 256;
            int kk = lin >> 5;
            int n4 = (lin & 31) * 4;
            long long off = (long long)z * sB + (long long)(k0 + kk) * N + n0 + n4;
            short4 h = *(const short4*)(Bh_ + off);
            short4 l = *(const short4*)(Bl_ + off);
            Bs[kk][n4 + 0] = bf2f(h.x) + bf2f(l.x);
            Bs[kk][n4 + 1] = bf2f(h.y) + bf2f(l.y);
            Bs[kk][n4 + 2] = bf2f(h.z) + bf2f(l.z);
            Bs[kk][n4 + 3] = bf2f(h.w) + bf2f(l.w);
        }
        __syncthreads();

        #pragma unroll
        for (int kk = 0; kk < 16; ++kk) {
            float a[8], b[8];
            *(float4*)&a[0] = *(const float4*)&As[kk][ty * 8];
            *(float4*)&a[4] = *(const float4*)&As[kk][ty * 8 + 4];
            *(float4*)&b[0] = *(const float4*)&Bs[kk][tx * 8];
            *(float4*)&b[4] = *(const float4*)&Bs[kk][tx * 8 + 4];
            #pragma unroll
            for (int i = 0; i < 8; ++i)
                #pragma unroll
                for (int j = 0; j < 8; ++j)
                    accv[i][j] = fmaf(a[i], b[j], accv[i][j]);
        }
        __syncthreads();
    }

    #pragma unroll
    for (int i = 0; i < 8; ++i) {
        int rowl = m0 + ty * 8 + i;
        long long base = (long long)z * sB + (long long)rowl * N;
        #pragma unroll
        for (int j = 0; j < 8; ++j) {
            int col = n0 + tx * 8 + j;
            long long idx = base + col;
            float v = accv[i][j];
            if (ACC) v += bf2f(Ch[idx]) + bf2f(Cl[idx]);
            short hh, ll;
            split1(v, hh, ll);
            Ch[idx] = hh;
            Cl[idx] = ll;
        }
    }
}

// ---------------- fp64-accumulate affinity GEMM ----------------
__global__ __launch_bounds__(256) void gemm_bt_f64(
    const float* __restrict__ A,
    const short* __restrict__ Bh_, const short* __restrict__ Bl_,
    float* __restrict__ C)
{
    __shared__ float As[16][65];
    __shared__ float Bs[16][65];

    const int K = 2048;
    int z = blockIdx.z;
    const float* Az = A + (long long)z * 524288;
    C += (long long)z * 65536;

    int n0 = blockIdx.x * 64;
    int m0 = blockIdx.y * 64;
    int tid = threadIdx.x;
    int tx = tid & 15;
    int ty = tid >> 4;

    double acc[4][4];
    #pragma unroll
    for (int i = 0; i < 4; ++i)
        #pragma unroll
        for (int j = 0; j < 4; ++j) acc[i][j] = 0.0;

    int r  = tid >> 2;
    int c4 = (tid & 3) * 4;

    for (int k0 = 0; k0 < K; k0 += 16) {
        {
            const float4 v = *(const float4*)(Az + (long long)(m0 + r) * K + k0 + c4);
            As[c4 + 0][r] = v.x; As[c4 + 1][r] = v.y;
            As[c4 + 2][r] = v.z; As[c4 + 3][r] = v.w;
        }
        {
            long long off = (long long)z * 524288 + (long long)(n0 + r) * K + k0 + c4;
            short4 h = *(const short4*)(Bh_ + off);
            short4 l = *(const short4*)(Bl_ + off);
            Bs[c4 + 0][r] = bf2f(h.x) + bf2f(l.x);
            Bs[c4 + 1][r] = bf2f(h.y) + bf2f(l.y);
            Bs[c4 + 2][r] = bf2f(h.z) + bf2f(l.z);
            Bs[c4 + 3][r] = bf2f(h.w) + bf2f(l.w);
        }
        __syncthreads();

        #pragma unroll
        for (int kk = 0; kk < 16; ++kk) {
            double a[4], b[4];
            #pragma unroll
            for (int i = 0; i < 4; ++i) a[i] = (double)As[kk][ty + 16 * i];
            #pragma unroll
            for (int j = 0; j < 4; ++j) b[j] = (double)Bs[kk][tx + 16 * j];
            #pragma unroll
            for (int i = 0; i < 4; ++i)
                #pragma unroll
                for (int j = 0; j < 4; ++j)
                    acc[i][j] = fma(a[i], b[j], acc[i][j]);
        }
        __syncthreads();
    }

    #pragma unroll
    for (int i = 0; i < 4; ++i) {
        int rowl = m0 + ty + 16 * i;
        #pragma unroll
        for (int j = 0; j < 4; ++j)
            C[(long long)rowl * 256 + n0 + tx + 16 * j] = (float)acc[i][j];
    }
}

// =====================================================================
// Fused Sinkhorn: one 1024-thread block per batch; S register-resident.
// Thread (w = wave 0..15, l = lane 0..63): rows w*16..w*16+15, cols 4l..4l+3.
// 10 iterations (even: row-lse via wave shuffles; odd: col-lse via
// thread-local partials + LDS cross-wave combine). Final: exp, masked 0.
// =====================================================================
__global__ __launch_bounds__(1024, 4) void sk_fused(float* __restrict__ S,
                                                    const int* __restrict__ n1)
{
    __shared__ float pmax[16][256];
    __shared__ float psum[16][256];
    __shared__ float lseS[256];

    const int b = blockIdx.x;
    const int tid = threadIdx.x;
    const int w = tid >> 6, l = tid & 63;
    const int lim = n1[b];
    float* Sb = S + (long long)b * 65536;

    float4 v[16];
    #pragma unroll
    for (int r = 0; r < 16; ++r) {
        int n = w * 16 + r;
        if (n < lim) {
            float4 x = *(const float4*)(Sb + n * 256 + l * 4);
            v[r].x = x.x / SK_TAU; v[r].y = x.y / SK_TAU;
            v[r].z = x.z / SK_TAU; v[r].w = x.w / SK_TAU;
        } else {
            v[r] = (float4){NEGV, NEGV, NEGV, NEGV};
        }
    }

    for (int it = 0; it < 10; ++it) {
        if ((it & 1) == 0) {
            // ---- row normalize (axis=2); rows are wave-uniform ----
            #pragma unroll
            for (int r = 0; r < 16; ++r) {
                if (w * 16 + r >= lim) continue;
                float m = fmaxf(fmaxf(v[r].x, v[r].y), fmaxf(v[r].z, v[r].w));
                #pragma unroll
                for (int off = 1; off < 64; off <<= 1) m = fmaxf(m, __shfl_xor(m, off));
                float s = expf(v[r].x - m) + expf(v[r].y - m) +
                          expf(v[r].z - m) + expf(v[r].w - m);
                #pragma unroll
                for (int off = 1; off < 64; off <<= 1) s += __shfl_xor(s, off);
                float lse = m + logf(s);
                v[r].x -= lse; v[r].y -= lse; v[r].z -= lse; v[r].w -= lse;
            }
        } else {
            // ---- col normalize (axis=1) ----
            float cm[4] = {-3.4e38f, -3.4e38f, -3.4e38f, -3.4e38f};
            #pragma unroll
            for (int r = 0; r < 16; ++r) {
                cm[0] = fmaxf(cm[0], v[r].x); cm[1] = fmaxf(cm[1], v[r].y);
                cm[2] = fmaxf(cm[2], v[r].z); cm[3] = fmaxf(cm[3], v[r].w);
            }
            float cs[4] = {0.f, 0.f, 0.f, 0.f};
            #pragma unroll
            for (int r = 0; r < 16; ++r) {
                cs[0] += expf(v[r].x - cm[0]); cs[1] += expf(v[r].y - cm[1]);
                cs[2] += expf(v[r].z - cm[2]); cs[3] += expf(v[r].w - cm[3]);
            }
            #pragma unroll
            for (int j = 0; j < 4; ++j) {
                pmax[w][l * 4 + j] = cm[j];
                psum[w][l * 4 + j] = cs[j];
            }
            __syncthreads();
            if (tid < 256) {
                float m = -3.4e38f, s = 0.f;
                #pragma unroll
                for (int ww = 0; ww < 16; ++ww) {
                    float pm = pmax[ww][tid], ps = psum[ww][tid];
                    float nm = fmaxf(m, pm);
                    s = s * expf(m - nm) + ps * expf(pm - nm);
                    m = nm;
                }
                lseS[tid] = m + logf(s);
            }
            __syncthreads();
            float l0 = lseS[l * 4 + 0], l1 = lseS[l * 4 + 1];
            float l2 = lseS[l * 4 + 2], l3 = lseS[l * 4 + 3];
            #pragma unroll
            for (int r = 0; r < 16; ++r) {
                if (w * 16 + r >= lim) continue;
                v[r].x -= l0; v[r].y -= l1; v[r].z -= l2; v[r].w -= l3;
            }
        }
    }

    // ---- final: exp, masked rows -> 0 ----
    #pragma unroll
    for (int r = 0; r < 16; ++r) {
        int n = w * 16 + r;
        float4 o;
        if (n < lim) {
            o.x = expf(v[r].x); o.y = expf(v[r].y);
            o.z = expf(v[r].z); o.w = expf(v[r].w);
        } else {
            o = (float4){0.f, 0.f, 0.f, 0.f};
        }
        *(float4*)(Sb + n * 256 + l * 4) = o;
    }
}

// ---------------- launch wrappers ----------------
static void gsp(hipStream_t st, int om, const short* Ah, const short* Al,
                const short* Bh, const short* Bl, int Ns, int K,
                float* Cf, short* Ch, short* Cl, const float* bias, int relu)
{
    dim3 grid(Ns / 128, 64), block(256);
    if (om == 0)
        gemm_dma<0><<<grid, block, 0, st>>>(Ah, Al, Bh, Bl, K, Cf, nullptr, nullptr, 2048, bias, relu);
    else if (om == 1)
        gemm_dma<1><<<grid, block, 0, st>>>(Ah, Al, Bh, Bl, K, nullptr, Ch, Cl, 2048, bias, relu);
    else
        gemm_dma<2><<<grid, block, 0, st>>>(Ah, Al, Bh, Bl, K, nullptr, Ch, Cl, 2048, bias, relu);
}

static void gsc(hipStream_t st, int om, const short* Ah, const short* Al,
                const float* Bf, short* Ch, short* Cl, const float* bias)
{
    dim3 grid(16, 64), block(256);
    if (om == 1)
        gemm_cvt<1><<<grid, block, 0, st>>>(Ah, Al, Bf, 2048, 2048, Ch, Cl, 2048, bias);
    else
        gemm_cvt<2><<<grid, block, 0, st>>>(Ah, Al, Bf, 2048, 2048, Ch, Cl, 2048, bias);
}

static void wsp(hipStream_t st, const float* W, int Krows, int c0, int ncols,
                short* H, short* L)
{
    dim3 grid(Krows / 32, ncols / 32);
    wsplit_t<<<grid, 256, 0, st>>>(W, 2048, c0, H, L, Krows);
}

// ---------------- driver ----------------
extern "C" void kernel_launch(void* const* d_in, const int* in_sizes, int n_in,
                              void* d_out, int out_size, void* d_ws, size_t ws_size,
                              hipStream_t stream)
{
    const float* feat1 = (const float*)d_in[0];
    const float* feat2 = (const float*)d_in[1];
    const float* A1    = (const float*)d_in[2];
    const float* A2    = (const float*)d_in[3];
    const int*   n1    = (const int*)d_in[4];
    const float* W0a = (const float*)d_in[8];  const float* b0a = (const float*)d_in[9];
    const float* W0u = (const float*)d_in[10]; const float* b0u = (const float*)d_in[11];
    const float* W1a = (const float*)d_in[12]; const float* b1a = (const float*)d_in[13];
    const float* W1u = (const float*)d_in[14]; const float* b1u = (const float*)d_in[15];
    const float* Wc  = (const float*)d_in[16]; const float* bc  = (const float*)d_in[17];
    const float* Aaff0 = (const float*)d_in[18];
    const float* Aaff1 = (const float*)d_in[19];

    const long long TSZ = 16777216LL;
    const long long PL  = 16777216LL;
    const long long PF  = 8388608LL;

    float* T1f = (float*)d_ws;
    float* T2f = T1f + TSZ;
    float* T3f = T2f + TSZ;
    float* T4f = T3f + TSZ;
    short *T1h = (short*)T1f, *T1l = T1h + PL;
    short *T2h = (short*)T2f, *T2l = T2h + PL;
    short *T3h = (short*)T3f, *T3l = T3h + PL;
    short *T4h = (short*)T4f, *T4l = T4h + PL;

    short* f1h = (short*)T4f;      short* f1l = f1h + PF;
    short* f2h = f1h + 2 * PF;     short* f2l = f1h + 3 * PF;
    float* invA = (float*)T4f;
    float* invB = invA + 8192;

    float* S   = (float*)d_out;
    short* swh = (short*)d_out;
    short* swl = swh + 2097152;
    float* inv1 = S;
    float* inv2 = S + 8192;

    dim3 bgrid(16, 2, 32), bblk(256);

    // ===== Phase 0: split feats =====
    split_mat<<<2048, 256, 0, stream>>>(feat1, f1h, f1l, 8192LL * 1024 / 4);
    split_mat<<<2048, 256, 0, stream>>>(feat2, f2h, f2l, 8192LL * 1024 / 4);

    // ===== Phase 1: gconv layer 0 =====
    wsp(stream, W0u, 1024, 0, 2048, swh, swl);
    gsp(stream, 1, f1h, f1l, swh, swl, 2048, 1024, nullptr, T1h, T1l, b0u, 1);
    gsp(stream, 1, f2h, f2l, swh, swl, 2048, 1024, nullptr, T2h, T2l, b0u, 1);
    wsp(stream, W0a, 1024, 0, 2048, swh, swl);
    gsp(stream, 1, f1h, f1l, swh, swl, 2048, 1024, nullptr, T3h, T3l, b0a, 1);
    colnorm_k<<<32, 256, 0, stream>>>(A1, invA);
    colnorm_k<<<32, 256, 0, stream>>>(A2, invB);
    bgemm<false, true><<<bgrid, bblk, 0, stream>>>(A1, T3h, T3l, T1h, T1l, invA);
    gsp(stream, 1, f2h, f2l, swh, swl, 2048, 1024, nullptr, T3h, T3l, b0a, 1);
    bgemm<false, true><<<bgrid, bblk, 0, stream>>>(A2, T3h, T3l, T2h, T2l, invB);

    // ===== Phase 2: affinity 0 =====
    wsp(stream, Aaff0, 2048, 0, 1024, swh, swl);
    gsp(stream, 0, T1h, T1l, swh, swl, 1024, 2048, T3f + 0, nullptr, nullptr, nullptr, 0);
    wsp(stream, Aaff0, 2048, 1024, 1024, swh, swl);
    gsp(stream, 0, T1h, T1l, swh, swl, 1024, 2048, T3f + 1024, nullptr, nullptr, nullptr, 0);
    gemm_bt_f64<<<dim3(4, 4, 32), 256, 0, stream>>>(T3f, T2h, T2l, S);

    sk_fused<<<32, 1024, 0, stream>>>(S, n1);

    // ===== Phase 4: cross-graph update =====
    bgemm<false, false><<<bgrid, bblk, 0, stream>>>(S, T2h, T2l, T3h, T3l, nullptr);   // c1
    gsc(stream, 1, T1h, T1l, Wc,           T4h, T4l, bc);        // new1 (p alive)
    gsc(stream, 2, T3h, T3l, Wc + 4194304, T4h, T4l, nullptr);
    bgemm<true, false><<<bgrid, bblk, 0, stream>>>(S, T1h, T1l, T3h, T3l, nullptr);    // c2; p dead
    wsp(stream, Wc, 2048, 0, 1024, swh, swl);
    gsp(stream, 1, T2h, T2l, swh, swl, 1024, 2048, nullptr, T1h + 0,    T1l + 0,    bc, 0);
    wsp(stream, Wc, 2048, 1024, 1024, swh, swl);
    gsp(stream, 1, T2h, T2l, swh, swl, 1024, 2048, nullptr, T1h + 1024, T1l + 1024, bc + 1024, 0);
    wsp(stream, Wc + 4194304, 2048, 0, 1024, swh, swl);
    gsp(stream, 2, T3h, T3l, swh, swl, 1024, 2048, nullptr, T1h + 0,    T1l + 0,    nullptr, 0);
    wsp(stream, Wc + 4194304, 2048, 1024, 1024, swh, swl);
    gsp(stream, 2, T3h, T3l, swh, swl, 1024, 2048, nullptr, T1h + 1024, T1l + 1024, nullptr, 0);

    // ===== Phase 5: gconv layer 1 =====
    wsp(stream, W1a, 2048, 0, 1024, swh, swl);
    gsp(stream, 1, T4h, T4l, swh, swl, 1024, 2048, nullptr, T2h + 0,    T2l + 0,    b1a, 1);
    wsp(stream, W1a, 2048, 1024, 1024, swh, swl);
    gsp(stream, 1, T4h, T4l, swh, swl, 1024, 2048, nullptr, T2h + 1024, T2l + 1024, b1a + 1024, 1);
    wsp(stream, W1u, 2048, 0, 1024, swh, swl);
    gsp(stream, 1, T4h, T4l, swh, swl, 1024, 2048, nullptr, T3h + 0,    T3l + 0,    b1u, 1);
    wsp(stream, W1u, 2048, 1024, 1024, swh, swl);
    gsp(stream, 1, T4h, T4l, swh, swl, 1024, 2048, nullptr, T3h + 1024, T3l + 1024, b1u + 1024, 1);
    colnorm_k<<<32, 256, 0, stream>>>(A1, inv1);
    bgemm<false, true><<<bgrid, bblk, 0, stream>>>(A1, T2h, T2l, T3h, T3l, inv1);
    wsp(stream, W1a, 2048, 0, 1024, swh, swl);
    gsp(stream, 1, T1h, T1l, swh, swl, 1024, 2048, nullptr, T2h + 0,    T2l + 0,    b1a, 1);
    wsp(stream, W1a, 2048, 1024, 1024, swh, swl);
    gsp(stream, 1, T1h, T1l, swh, swl, 1024, 2048, nullptr, T2h + 1024, T2l + 1024, b1a + 1024, 1);
    wsp(stream, W1u, 2048, 0, 1024, swh, swl);
    gsp(stream, 1, T1h, T1l, swh, swl, 1024, 2048, nullptr, T4h + 0,    T4l + 0,    b1u, 1);
    wsp(stream, W1u, 2048, 1024, 1024, swh, swl);
    gsp(stream, 1, T1h, T1l, swh, swl, 1024, 2048, nullptr, T4h + 1024, T4l + 1024, b1u + 1024, 1);
    colnorm_k<<<32, 256, 0, stream>>>(A2, inv2);
    bgemm<false, true><<<bgrid, bblk, 0, stream>>>(A2, T2h, T2l, T4h, T4l, inv2);

    // ===== Phase 6: affinity 1 =====
    wsp(stream, Aaff1, 2048, 0, 1024, swh, swl);
    gsp(stream, 0, T3h, T3l, swh, swl, 1024, 2048, T1f + 0, nullptr, nullptr, nullptr, 0);
    wsp(stream, Aaff1, 2048, 1024, 1024, swh, swl);
    gsp(stream, 0, T3h, T3l, swh, swl, 1024, 2048, T1f + 1024, nullptr, nullptr, nullptr, 0);
    gemm_bt_f64<<<dim3(4, 4, 32), 256, 0, stream>>>(T1f, T4h, T4l, S);

    sk_fused<<<32, 1024, 0, stream>>>(S, n1);
}